// Round 1
// 489.141 us; speedup vs baseline: 1.2544x; 1.2544x over previous
//
#include <hip/hip_runtime.h>
#include <math.h>

#define L_LEN 4500
#define T2 128
#define NT2 36    // ceil(4500/128)
#define KSPL 12   // K-splits for corr_k
#define KT 128    // corr K-tile (elements)
#define TW 148    // LDS row stride in words (KT+16 real + 4 pad; 148/4=37 odd -> conflict-free b128)
#define NTILE 36  // K-tiles per n (36*128 >= 4500)

typedef _Float16 half8 __attribute__((ext_vector_type(8)));
typedef float f32x16 __attribute__((ext_vector_type(16)));

__device__ __forceinline__ half8 mk_half8(unsigned int w0, unsigned int w1,
                                          unsigned int w2, unsigned int w3) {
    union { unsigned int u[4]; half8 h; } t;
    t.u[0] = w0; t.u[1] = w1; t.u[2] = w2; t.u[3] = w3;
    return t.h;
}

#define LOPAIR(a, b) (((a) & 0xffffu) | ((b) << 16))
#define HIPAIR(a, b) (((a) >> 16) | ((b) & 0xffff0000u))

// ---------------- prep: transpose conv2 weights to [cin][g][k] ----------------
__global__ void prep_w2t_k(const float* __restrict__ w2, float* __restrict__ w2t) {
    int i = blockIdx.x * 256 + threadIdx.x;
    if (i < 64 * 64 * 5) {
        int k = i / 320;
        int r = i - k * 320;
        int c = r / 5;
        int g = r - c * 5;
        w2t[(c * 5 + g) * 64 + k] = w2[i];
    }
}

// ---- conv12_k: fused conv1 (k=7) + conv2 (k=5) : x -> h2, no h1 round-trip ---
__global__ __launch_bounds__(256) void conv12_k(const float* __restrict__ x,
                                                const float* __restrict__ w1,
                                                const float* __restrict__ w2t,
                                                float* __restrict__ h2) {
    __shared__ float xs[144];
    __shared__ __align__(16) float h1s[64 * 132];
    int n = blockIdx.x / NT2;
    int t = blockIdx.x - n * NT2;
    int l0 = t * T2;
    const float* xr = x + (size_t)n * L_LEN;
    if (threadIdx.x < 138) {
        int l = l0 - 5 + threadIdx.x;
        xs[threadIdx.x] = (l >= 0 && l < L_LEN) ? xr[l] : 0.f;
    }
    __syncthreads();
    {
        int vci = threadIdx.x >> 2;
        int seg = threadIdx.x & 3;
        int j0 = seg * 33;
        float w[7];
#pragma unroll
        for (int g = 0; g < 7; ++g) w[g] = w1[vci * 7 + g];
        for (int jj = 0; jj < 33; ++jj) {
            int j = j0 + jj;
            int l = l0 - 2 + j;
            float a = 0.f;
#pragma unroll
            for (int g = 0; g < 7; ++g) a += w[g] * xs[j + g];
            h1s[vci * 132 + j] = (l >= 0 && l < L_LEN) ? a : 0.f;   // SAME-pad zeroing
        }
    }
    __syncthreads();
    int ta = threadIdx.x & 15;
    int tb = threadIdx.x >> 4;
    int k0 = ta * 4;
    int lt = tb * 8;
    float acc[4][8];
#pragma unroll
    for (int kq = 0; kq < 4; ++kq)
#pragma unroll
        for (int m = 0; m < 8; ++m) acc[kq][m] = 0.f;
    for (int ci = 0; ci < 64; ++ci) {
        const float* hrow = &h1s[ci * 132 + lt];
        float4 wa = *(const float4*)hrow;
        float4 wb = *(const float4*)(hrow + 4);
        float4 wc = *(const float4*)(hrow + 8);
        float win[12] = {wa.x, wa.y, wa.z, wa.w, wb.x, wb.y, wb.z, wb.w,
                         wc.x, wc.y, wc.z, wc.w};
        const float* wp = w2t + ci * 320 + k0;
#pragma unroll
        for (int g = 0; g < 5; ++g) {
            float4 wv = *(const float4*)(wp + g * 64);
#pragma unroll
            for (int m = 0; m < 8; ++m) {
                acc[0][m] += wv.x * win[m + g];
                acc[1][m] += wv.y * win[m + g];
                acc[2][m] += wv.z * win[m + g];
                acc[3][m] += wv.w * win[m + g];
            }
        }
    }
    int lbase = l0 + lt;
#pragma unroll
    for (int kq = 0; kq < 4; ++kq) {
        float* orow = h2 + ((size_t)n * 64 + k0 + kq) * L_LEN + lbase;
        if (lbase < L_LEN) {
            float4 s0 = {acc[kq][0], acc[kq][1], acc[kq][2], acc[kq][3]};
            *(float4*)orow = s0;
        }
        if (lbase + 4 < L_LEN) {
            float4 s1 = {acc[kq][4], acc[kq][5], acc[kq][6], acc[kq][7]};
            *(float4*)(orow + 4) = s1;
        }
    }
}

// ---------- sumstat_k: per (n,k) row -> sq (sum of squares), rowsum ----------
__global__ __launch_bounds__(256) void sumstat_k(const float* __restrict__ h2,
                                                 float* __restrict__ sq,
                                                 float* __restrict__ rowsum) {
    int nk = blockIdx.x;
    const float4* row = (const float4*)(h2 + (size_t)nk * L_LEN);
    float s = 0.f, r = 0.f;
    for (int i = threadIdx.x; i < L_LEN / 4; i += 256) {
        float4 v = row[i];
        s += v.x * v.x + v.y * v.y + v.z * v.z + v.w * v.w;
        r += v.x + v.y + v.z + v.w;
    }
#pragma unroll
    for (int off = 32; off; off >>= 1) {
        s += __shfl_down(s, off);
        r += __shfl_down(r, off);
    }
    __shared__ float ss[4], rr[4];
    if ((threadIdx.x & 63) == 0) { ss[threadIdx.x >> 6] = s; rr[threadIdx.x >> 6] = r; }
    __syncthreads();
    if (threadIdx.x == 0) {
        sq[nk] = ss[0] + ss[1] + ss[2] + ss[3];
        rowsum[nk] = rr[0] + rr[1] + rr[2] + rr[3];
    }
}

// ---- corr_k (MFMA): R[a][b][d] = sum_l h2[a][l] * h2[b][l+d-2]  (OOB=0) -----
// f16 hi/lo split (hi=f16(x), lo=f16(x-hi)), 3x v_mfma_f32_32x32x16_f16 per
// product (hi*hi + hi*lo + lo*hi; lo*lo ~2^-24 dropped) => fp32-grade R.
// LDS: 64 rows x TW interleaved (hi|lo<<16) words; stride 148 (odd chunk
// stride) => conflict-free ds_read_b128. 4 waves = 2x2 (a,b) 32-quadrants,
// each owns all 5 shifts: acc = 5 x f32x16. A-frag reads 2 chunks, B shifted
// window reads 4 chunks; every shift builds frag words from 2 adjacent words.
// XCD-bijective swizzle: all KSPL split-blocks of one n land on one XCD so
// h2[n] (1.1 MB) is L2-resident. Rp layout: [s][d][a][b] (coalesced stores).
__global__ __launch_bounds__(256, 3) void corr_k(const float* __restrict__ h2,
                                                 float* __restrict__ Rp) {
    __shared__ __align__(16) unsigned int hl[64 * TW];   // 37,888 B
    int bid = blockIdx.x;
    int xcd = bid & 7;
    int r8 = bid >> 3;            // 0..95
    int n = xcd * 8 + (r8 & 7);   // all 12 splits of n share an XCD
    int s = r8 >> 3;              // 0..11
    const float* h2n = h2 + (size_t)n * 64 * L_LEN;

    int lane = threadIdx.x & 63;
    int wid = threadIdx.x >> 6;
    int a0 = (wid >> 1) * 32;
    int b0 = (wid & 1) * 32;
    int row31 = lane & 31;
    int g = lane >> 5;

    f32x16 acc[5];
#pragma unroll
    for (int d = 0; d < 5; ++d)
#pragma unroll
        for (int i = 0; i < 16; ++i) acc[d][i] = 0.f;

    int trow = threadIdx.x >> 2;   // staging row 0..63
    int tc4 = threadIdx.x & 3;     // staging chunk phase

    const unsigned int* arow = &hl[(a0 + row31) * TW + (g << 3)];
    const unsigned int* brow = &hl[(b0 + row31) * TW + (g << 3)];

    for (int tt = 0; tt < 3; ++tt) {
        int t = s + tt * KSPL;     // tile 0..35
        int l0 = t * KT;
        __syncthreads();           // protect previous tile's readers
        // ---- stage 64 x 144 words: (f16 hi | f16 lo<<16) per element ----
        for (int i = 0; i < 9; ++i) {
            int c = tc4 + (i << 2);            // chunk 0..35
            int lbase = l0 - 8 + (c << 2);
            float v[4];
            if (lbase >= 0 && lbase + 3 < L_LEN) {
                float4 f = *(const float4*)(h2n + (size_t)trow * L_LEN + lbase);
                v[0] = f.x; v[1] = f.y; v[2] = f.z; v[3] = f.w;
            } else {
#pragma unroll
                for (int q = 0; q < 4; ++q) {
                    int l = lbase + q;
                    v[q] = (l >= 0 && l < L_LEN) ? h2n[(size_t)trow * L_LEN + l] : 0.f;
                }
            }
            unsigned int wv[4];
#pragma unroll
            for (int q = 0; q < 4; ++q) {
                float xv = v[q];
                _Float16 hi = (_Float16)xv;
                float hif = (float)hi;
                _Float16 lo = (_Float16)(xv - hif);
                unsigned short hb = __builtin_bit_cast(unsigned short, hi);
                unsigned short lb = __builtin_bit_cast(unsigned short, lo);
                wv[q] = (unsigned int)hb | ((unsigned int)lb << 16);
            }
            uint4 uu; uu.x = wv[0]; uu.y = wv[1]; uu.z = wv[2]; uu.w = wv[3];
            *(uint4*)&hl[trow * TW + (c << 2)] = uu;
        }
        __syncthreads();
        // ---- 8 K-steps of 16: 15 mfma each (5 shifts x 3 split products) ----
#pragma unroll
        for (int ks = 0; ks < 8; ++ks) {
            const int u0 = 8 + ks * 16;        // word offset (g folded into arow/brow)
            uint4 va0 = *(const uint4*)(arow + u0);
            uint4 va1 = *(const uint4*)(arow + u0 + 4);
            uint4 vb0 = *(const uint4*)(brow + u0 - 4);
            uint4 vb1 = *(const uint4*)(brow + u0);
            uint4 vb2 = *(const uint4*)(brow + u0 + 4);
            uint4 vb3 = *(const uint4*)(brow + u0 + 8);
            unsigned int WA[8] = {va0.x, va0.y, va0.z, va0.w, va1.x, va1.y, va1.z, va1.w};
            unsigned int V[16] = {vb0.x, vb0.y, vb0.z, vb0.w, vb1.x, vb1.y, vb1.z, vb1.w,
                                  vb2.x, vb2.y, vb2.z, vb2.w, vb3.x, vb3.y, vb3.z, vb3.w};
            half8 Ahi = mk_half8(LOPAIR(WA[0], WA[1]), LOPAIR(WA[2], WA[3]),
                                 LOPAIR(WA[4], WA[5]), LOPAIR(WA[6], WA[7]));
            half8 Alo = mk_half8(HIPAIR(WA[0], WA[1]), HIPAIR(WA[2], WA[3]),
                                 HIPAIR(WA[4], WA[5]), HIPAIR(WA[6], WA[7]));
#pragma unroll
            for (int d = 0; d < 5; ++d) {
                half8 Bhi = mk_half8(LOPAIR(V[d + 2], V[d + 3]), LOPAIR(V[d + 4], V[d + 5]),
                                     LOPAIR(V[d + 6], V[d + 7]), LOPAIR(V[d + 8], V[d + 9]));
                half8 Blo = mk_half8(HIPAIR(V[d + 2], V[d + 3]), HIPAIR(V[d + 4], V[d + 5]),
                                     HIPAIR(V[d + 6], V[d + 7]), HIPAIR(V[d + 8], V[d + 9]));
                acc[d] = __builtin_amdgcn_mfma_f32_32x32x16_f16(Alo, Bhi, acc[d], 0, 0, 0);
                acc[d] = __builtin_amdgcn_mfma_f32_32x32x16_f16(Ahi, Blo, acc[d], 0, 0, 0);
                acc[d] = __builtin_amdgcn_mfma_f32_32x32x16_f16(Ahi, Bhi, acc[d], 0, 0, 0);
            }
        }
    }
    // ---- write partials: Rp[n*KSPL+s][d*4096 + a*64 + b] ----
    float* base = Rp + (size_t)(n * KSPL + s) * 20480;
#pragma unroll
    for (int d = 0; d < 5; ++d) {
#pragma unroll
        for (int rg = 0; rg < 16; ++rg) {
            int crow = (rg & 3) + 8 * (rg >> 2) + 4 * g;
            base[d * 4096 + (a0 + crow) * 64 + b0 + row31] = acc[d][rg];
        }
    }
}

// ---------- reduce_k: element-wise sum of the KSPL partials ------------------
__global__ __launch_bounds__(256) void reduce_k(const float* __restrict__ Rp,
                                                float* __restrict__ Rsum) {
    int n = blockIdx.x / 80;
    int bb = blockIdx.x - n * 80;
    int idx = bb * 256 + threadIdx.x;
    float s = 0.f;
#pragma unroll
    for (int s2 = 0; s2 < KSPL; ++s2) s += Rp[((size_t)n * KSPL + s2) * 20480 + idx];
    Rsum[(size_t)n * 20480 + idx] = s;
}

// ---- mcoef_k: assemble M[c][36] from R + bias/edge terms, then routing ------
__global__ __launch_bounds__(256) void mcoef_k(const float* __restrict__ Rsum,
                                               const float* __restrict__ h2,
                                               const float* __restrict__ sq,
                                               const float* __restrict__ rowsum,
                                               const float* __restrict__ wA,
                                               const float* __restrict__ bA,
                                               float* __restrict__ coefb) {
    __shared__ float Rsub[320];
    __shared__ float Mred[64 * 36];
    __shared__ float s0s[64], s1s[64], Ts[64], invs[64];
    int n = blockIdx.x;
    int c = threadIdx.x & 63;
    int sub = threadIdx.x >> 6;
    if (threadIdx.x < 64) {
        int a = threadIdx.x;
        s0s[a] = h2[((size_t)n * 64 + a) * L_LEN + 0];
        s1s[a] = h2[((size_t)n * 64 + a) * L_LEN + (L_LEN - 1)];
        Ts[a]  = rowsum[n * 64 + a];
        invs[a] = 1.f / (1.f + sq[n * 64 + a]);
    }
    float wreg[24];
#pragma unroll
    for (int q = 0; q < 24; ++q) wreg[q] = wA[c * 24 + q];
    float bc = bA[c];
    __syncthreads();
    float SG[8];
#pragma unroll
    for (int i = 0; i < 8; ++i) {
        float s = 0.f;
#pragma unroll
        for (int p = 0; p < 8; ++p) {
            int a = 8 * i + p;
            float Ta = Ts[a];
            s += invs[a] * (wreg[p * 3 + 0] * (Ta - s1s[a]) +
                            wreg[p * 3 + 1] * Ta +
                            wreg[p * 3 + 2] * (Ta - s0s[a]));
        }
        SG[i] = s;
    }
    float M36[36];
    int ij = 0;
#pragma unroll
    for (int i = 0; i < 8; ++i) {
#pragma unroll
        for (int j = i; j < 8; ++j) {
            __syncthreads();
            for (int fidx = threadIdx.x; fidx < 320; fidx += 256) {
                int p = fidx / 40;
                int r = fidx - 40 * p;
                int pp = r / 5;
                int d = r - 5 * pp;
                int a = 8 * i + p, b = 8 * j + pp;
                Rsub[fidx] = Rsum[(size_t)n * 20480 + d * 4096 + a * 64 + b];
            }
            __syncthreads();
            float acc = 0.f;
#pragma unroll
            for (int pl = 0; pl < 2; ++pl) {
                int p = sub * 2 + pl;
                int a = 8 * i + p;
                float ia = invs[a];
                float w0 = wreg[p * 3], w1 = wreg[p * 3 + 1], w2v = wreg[p * 3 + 2];
                float e1a = s1s[a], e0a = s0s[a];
#pragma unroll
                for (int pp = 0; pp < 8; ++pp) {
                    int b = 8 * j + pp;
                    float q0 = wreg[pp * 3], q1 = wreg[pp * 3 + 1], q2 = wreg[pp * 3 + 2];
                    const float* R5 = &Rsub[(p * 8 + pp) * 5];
                    float term = (w2v * q0) * R5[0]
                               + (w1 * q0 + w2v * q1) * R5[1]
                               + (w0 * q0 + w1 * q1 + w2v * q2) * R5[2]
                               + (w0 * q1 + w1 * q2) * R5[3]
                               + (w0 * q2) * R5[4]
                               - (w0 * q0) * (e1a * s1s[b])
                               - (w2v * q2) * (e0a * s0s[b]);
                    acc += ia * invs[b] * term;
                }
            }
            M36[ij] = acc;
            ++ij;
        }
    }
    __syncthreads();
    if (sub == 0) {
#pragma unroll
        for (int q = 0; q < 36; ++q) Mred[c * 36 + q] = M36[q];
    }
    __syncthreads();
    if (sub == 1) {
#pragma unroll
        for (int q = 0; q < 36; ++q) Mred[c * 36 + q] += M36[q];
    }
    __syncthreads();
    if (sub == 2) {
#pragma unroll
        for (int q = 0; q < 36; ++q) Mred[c * 36 + q] += M36[q];
    }
    __syncthreads();
    if (sub == 3) {
#pragma unroll
        for (int q = 0; q < 36; ++q) Mred[c * 36 + q] += M36[q];
    }
    __syncthreads();
    if (threadIdx.x < 64) {
        float M[36];
        {
            int k2 = 0;
#pragma unroll
            for (int i = 0; i < 8; ++i)
#pragma unroll
                for (int j = i; j < 8; ++j, ++k2)
                    M[k2] = Mred[c * 36 + k2] + bc * (SG[i] + SG[j]) + 4500.f * bc * bc;
        }
        float rs[8];
#pragma unroll
        for (int i = 0; i < 8; ++i) rs[i] = 0.f;
        {
            int idx2 = 0;
#pragma unroll
            for (int i = 0; i < 8; ++i)
#pragma unroll
                for (int j = i; j < 8; ++j, ++idx2) {
                    rs[i] += M[idx2];
                    if (j > i) rs[j] += M[idx2];
                }
        }
        float sumAll = 0.f;
#pragma unroll
        for (int i = 0; i < 8; ++i) sumAll += rs[i];
        float sqn1 = sumAll * (1.f / 64.f);
        float binv = 1.f / (8.f * (1.f + sqn1));
        float bv[8], mx = -1e30f;
#pragma unroll
        for (int i = 0; i < 8; ++i) { bv[i] = rs[i] * binv; mx = fmaxf(mx, bv[i]); }
        float e[8], se = 0.f;
#pragma unroll
        for (int i = 0; i < 8; ++i) { e[i] = expf(bv[i] - mx); se += e[i]; }
        float sinv = 1.f / se;
        float ci_[8];
#pragma unroll
        for (int i = 0; i < 8; ++i) ci_[i] = e[i] * sinv;
        float sqn2 = 0.f;
        {
            int idx2 = 0;
#pragma unroll
            for (int i = 0; i < 8; ++i)
#pragma unroll
                for (int j = i; j < 8; ++j, ++idx2)
                    sqn2 += ((j > i) ? 2.f : 1.f) * ci_[i] * ci_[j] * M[idx2];
        }
        float scale = 1.f / (1.f + sqn2);
#pragma unroll
        for (int i = 0; i < 8; ++i) coefb[((size_t)n * 64 + c) * 8 + i] = ci_[i] * scale;
    }
}

// -------- weff_k: WeffT[n][a][g][c] = coef[n,c,a>>3]*W[c,a&7,g]*inv[n,a] ------
__global__ __launch_bounds__(256) void weff_k(const float* __restrict__ coefb,
                                              const float* __restrict__ wA,
                                              const float* __restrict__ sq,
                                              const float* __restrict__ bA,
                                              float* __restrict__ WeffT,
                                              float* __restrict__ vbias) {
    int n = blockIdx.x;
    for (int idx = threadIdx.x; idx < 12288; idx += 256) {
        int a = idx / 192;
        int r = idx - 192 * a;
        int g = r >> 6;
        int c = r & 63;
        float inv = 1.f / (1.f + sq[n * 64 + a]);
        WeffT[(size_t)n * 12288 + idx] =
            coefb[((size_t)n * 64 + c) * 8 + (a >> 3)] * wA[c * 24 + (a & 7) * 3 + g] * inv;
    }
    if (threadIdx.x < 64) {
        float s = 0.f;
#pragma unroll
        for (int i = 0; i < 8; ++i) s += coefb[((size_t)n * 64 + threadIdx.x) * 8 + i];
        vbias[n * 64 + threadIdx.x] = bA[threadIdx.x] * s;
    }
}

// ---- outconv_k: out = Weff (64->64, k=3) * h2 + vbias, register-tiled GEMM ---
__global__ __launch_bounds__(256) void outconv_k(const float* __restrict__ h2,
                                                 const float* __restrict__ WeffT,
                                                 const float* __restrict__ vbias,
                                                 float* __restrict__ out) {
    __shared__ __align__(16) float hs[64 * 132];
    int n = blockIdx.x / NT2;
    int t = blockIdx.x - n * NT2;
    int l0 = t * T2;
    const float* h2n = h2 + (size_t)n * 64 * L_LEN;
    for (int idx = threadIdx.x; idx < 64 * 130; idx += 256) {
        int ci = idx / 130;
        int j = idx - ci * 130;
        int l = l0 - 1 + j;
        hs[ci * 132 + j] = (l >= 0 && l < L_LEN) ? h2n[(size_t)ci * L_LEN + l] : 0.f;
    }
    __syncthreads();
    int ta = threadIdx.x & 15;
    int tb = threadIdx.x >> 4;
    int k0 = ta * 4;
    int lt = tb * 8;
    float acc[4][8];
#pragma unroll
    for (int kq = 0; kq < 4; ++kq)
#pragma unroll
        for (int m = 0; m < 8; ++m) acc[kq][m] = 0.f;
    const float* wbase = WeffT + (size_t)n * 12288 + k0;
    for (int ci = 0; ci < 64; ++ci) {
        const float* hrow = &hs[ci * 132 + lt];
        float4 wa = *(const float4*)hrow;
        float4 wb = *(const float4*)(hrow + 4);
        float4 wc = *(const float4*)(hrow + 8);
        float win[12] = {wa.x, wa.y, wa.z, wa.w, wb.x, wb.y, wb.z, wb.w,
                         wc.x, wc.y, wc.z, wc.w};
        const float* wp = wbase + ci * 192;
#pragma unroll
        for (int g = 0; g < 3; ++g) {
            float4 wv = *(const float4*)(wp + g * 64);
#pragma unroll
            for (int m = 0; m < 8; ++m) {
                acc[0][m] += wv.x * win[m + g];
                acc[1][m] += wv.y * win[m + g];
                acc[2][m] += wv.z * win[m + g];
                acc[3][m] += wv.w * win[m + g];
            }
        }
    }
    int lbase = l0 + lt;
#pragma unroll
    for (int kq = 0; kq < 4; ++kq) {
        float vb = vbias[n * 64 + k0 + kq];
        float* orow = out + ((size_t)n * 64 + k0 + kq) * L_LEN + lbase;
        if (lbase < L_LEN) {
            float4 s0 = {acc[kq][0] + vb, acc[kq][1] + vb, acc[kq][2] + vb, acc[kq][3] + vb};
            *(float4*)orow = s0;
        }
        if (lbase + 4 < L_LEN) {
            float4 s1 = {acc[kq][4] + vb, acc[kq][5] + vb, acc[kq][6] + vb, acc[kq][7] + vb};
            *(float4*)(orow + 4) = s1;
        }
    }
}

extern "C" void kernel_launch(void* const* d_in, const int* in_sizes, int n_in,
                              void* d_out, int out_size, void* d_ws, size_t ws_size,
                              hipStream_t stream) {
    const float* x  = (const float*)d_in[0];
    const float* w1 = (const float*)d_in[1];
    const float* w2 = (const float*)d_in[2];
    const float* wA = (const float*)d_in[3];
    const float* bA = (const float*)d_in[4];
    float* out = (float*)d_out;
    char* ws = (char*)d_ws;
    const size_t HB = (size_t)64 * 64 * L_LEN * 4;   // 73,728,000 B
    float* h2     = (float*)(ws + HB);
    float* sq     = (float*)(ws + 2 * HB);            // 16 KB
    float* rowsum = (float*)(ws + 2 * HB + 16384);    // 16 KB
    float* w2t    = (float*)(ws + 2 * HB + 32768);    // 80 KB
    // overlays in the first HB region:
    float* Rp    = (float*)ws;                        // 62,914,560 B
    float* Rsum  = (float*)(ws + 62914560);           //  5,242,880 B
    float* coefb = (float*)(ws + 68157440);           //    131,072 B
    float* WeffT = (float*)(ws + 68288512);           //  3,145,728 B
    float* vbias = (float*)(ws + 71434240);           //     16,384 B

    prep_w2t_k<<<80, 256, 0, stream>>>(w2, w2t);
    conv12_k<<<64 * NT2, 256, 0, stream>>>(x, w1, w2t, h2);
    sumstat_k<<<4096, 256, 0, stream>>>(h2, sq, rowsum);
    corr_k<<<64 * KSPL, 256, 0, stream>>>(h2, Rp);
    reduce_k<<<64 * 80, 256, 0, stream>>>(Rp, Rsum);
    mcoef_k<<<64, 256, 0, stream>>>(Rsum, h2, sq, rowsum, wA, bA, coefb);
    weff_k<<<64, 256, 0, stream>>>(coefb, wA, sq, bA, WeffT, vbias);
    outconv_k<<<64 * NT2, 256, 0, stream>>>(h2, WeffT, vbias, out);
}

// Round 2
// 412.657 us; speedup vs baseline: 1.4869x; 1.1853x over previous
//
#include <hip/hip_runtime.h>
#include <math.h>

#define L_LEN 4500
#define KSPL 12   // K-splits for corr_k
#define KT 128    // corr K-tile (elements)
#define TW 148    // corr LDS row stride in words
#define TL 256    // conv l-tile
#define NTB 18    // ceil(4500/256)
#define RS 72     // conv LDS plane row stride (f16 units); 16B-chunk stride 9 (odd) -> conflict-free b128

typedef _Float16 half8 __attribute__((ext_vector_type(8)));
typedef float f32x16 __attribute__((ext_vector_type(16)));

__device__ __forceinline__ half8 mk_half8(unsigned int w0, unsigned int w1,
                                          unsigned int w2, unsigned int w3) {
    union { unsigned int u[4]; half8 h; } t;
    t.u[0] = w0; t.u[1] = w1; t.u[2] = w2; t.u[3] = w3;
    return t.h;
}
__device__ __forceinline__ half8 u4_half8(uint4 v) {
    union { uint4 u; half8 h; } t; t.u = v; return t.h;
}

#define LOPAIR(a, b) (((a) & 0xffffu) | ((b) << 16))
#define HIPAIR(a, b) (((a) >> 16) | ((b) & 0xffff0000u))

// ------- prep: pack conv2 weights into MFMA A-fragment hi/lo u32 tables ------
// Layout: word i = ((kh*5+g)*4+ks)*256 + lane*4 + w ; elements j=2w,2w+1 of the
// A-frag for (kh,g,ks): k_out = kh*32+(lane&31), ci = ks*16+(lane>>5)*8+j.
__global__ void prep_w2f_k(const float* __restrict__ w2,
                           unsigned int* __restrict__ w2fh,
                           unsigned int* __restrict__ w2fl) {
    int i = blockIdx.x * 256 + threadIdx.x;
    if (i >= 10240) return;
    int w = i & 3;
    int t = i >> 2;
    int lane = t & 63; t >>= 6;
    int ks = t & 3; t >>= 2;          // t now 0..9
    int g = t % 5;
    int kh = t / 5;
    int k = kh * 32 + (lane & 31);
    int ci0 = ks * 16 + (lane >> 5) * 8 + w * 2;
    unsigned int hw = 0, lw = 0;
#pragma unroll
    for (int e = 0; e < 2; ++e) {
        float v = w2[(k * 64 + ci0 + e) * 5 + g];
        _Float16 hi = (_Float16)v;
        _Float16 lo = (_Float16)(v - (float)hi);
        unsigned short hb = __builtin_bit_cast(unsigned short, hi);
        unsigned short lb = __builtin_bit_cast(unsigned short, lo);
        hw |= ((unsigned int)hb) << (16 * e);
        lw |= ((unsigned int)lb) << (16 * e);
    }
    w2fh[i] = hw;
    w2fl[i] = lw;
}

// ---- conv12_k (MFMA): fused conv1(k=7) + conv2(k=5), f16 hi/lo 3-split ------
// Phase A: stage x window. Phase B: h1 transposed hi/lo f16 planes in LDS
// ([l_row][ci], row stride RS=72 -> conflict-free b128). Phase C: 20 (g,ks)
// steps x 12 mfma_32x32x16_f16; B-frag = 1 ds_read_b128 per plane (8 ci),
// A-frag = 1 dwordx4 per plane from L2-resident fragment table. Wave = 64k x
// 64l, block = 64k x 256l. Same n->XCD swizzle as corr_k for L2 locality.
__global__ __launch_bounds__(256, 2) void conv12_k(const float* __restrict__ x,
                                                   const float* __restrict__ w1,
                                                   const unsigned int* __restrict__ w2fh,
                                                   const unsigned int* __restrict__ w2fl,
                                                   float* __restrict__ h2) {
    __shared__ float xs[268];
    __shared__ __align__(16) _Float16 shh[260 * RS];
    __shared__ __align__(16) _Float16 shl[260 * RS];
    int b = blockIdx.x;
    int xcd = b & 7;
    int gi = xcd * 144 + (b >> 3);
    int n = gi / NTB;
    int t = gi - n * NTB;
    int l0 = t * TL;
    const float* xr = x + (size_t)n * L_LEN;
    for (int idx = threadIdx.x; idx < 266; idx += 256) {
        int l = l0 - 5 + idx;
        xs[idx] = (l >= 0 && l < L_LEN) ? xr[l] : 0.f;
    }
    __syncthreads();
    {
        int ci = threadIdx.x & 63;
        int q = threadIdx.x >> 6;
        float w[7];
#pragma unroll
        for (int g = 0; g < 7; ++g) w[g] = w1[ci * 7 + g];
        for (int tt = 0; tt < 65; ++tt) {
            int r = q * 65 + tt;
            int l = l0 + r - 2;
            float a = 0.f;
            if (l >= 0 && l < L_LEN) {
#pragma unroll
                for (int g = 0; g < 7; ++g) a += w[g] * xs[r + g];
            }
            _Float16 hi = (_Float16)a;
            _Float16 lo = (_Float16)(a - (float)hi);
            shh[r * RS + ci] = hi;
            shl[r * RS + ci] = lo;
        }
    }
    __syncthreads();
    int lane = threadIdx.x & 63;
    int wid = threadIdx.x >> 6;
    int col = lane & 31;
    int kg = lane >> 5;
    int lb0 = wid * 64 + col;
    f32x16 acc[2][2];
#pragma unroll
    for (int a1 = 0; a1 < 2; ++a1)
#pragma unroll
        for (int a2 = 0; a2 < 2; ++a2)
#pragma unroll
            for (int i = 0; i < 16; ++i) acc[a1][a2][i] = 0.f;
    const uint4* WH = (const uint4*)w2fh;
    const uint4* WL = (const uint4*)w2fl;
#pragma unroll
    for (int g = 0; g < 5; ++g) {
#pragma unroll
        for (int ks = 0; ks < 4; ++ks) {
            uint4 ah0 = WH[((0 * 5 + g) * 4 + ks) * 64 + lane];
            uint4 ah1 = WH[((1 * 5 + g) * 4 + ks) * 64 + lane];
            uint4 al0 = WL[((0 * 5 + g) * 4 + ks) * 64 + lane];
            uint4 al1 = WL[((1 * 5 + g) * 4 + ks) * 64 + lane];
            int off = ks * 16 + kg * 8;
            half8 bh0 = *(const half8*)&shh[(lb0 + g) * RS + off];
            half8 bl0 = *(const half8*)&shl[(lb0 + g) * RS + off];
            half8 bh1 = *(const half8*)&shh[(lb0 + 32 + g) * RS + off];
            half8 bl1 = *(const half8*)&shl[(lb0 + 32 + g) * RS + off];
            half8 Ah0 = u4_half8(ah0), Al0 = u4_half8(al0);
            half8 Ah1 = u4_half8(ah1), Al1 = u4_half8(al1);
            acc[0][0] = __builtin_amdgcn_mfma_f32_32x32x16_f16(Al0, bh0, acc[0][0], 0, 0, 0);
            acc[0][0] = __builtin_amdgcn_mfma_f32_32x32x16_f16(Ah0, bl0, acc[0][0], 0, 0, 0);
            acc[0][0] = __builtin_amdgcn_mfma_f32_32x32x16_f16(Ah0, bh0, acc[0][0], 0, 0, 0);
            acc[0][1] = __builtin_amdgcn_mfma_f32_32x32x16_f16(Al0, bh1, acc[0][1], 0, 0, 0);
            acc[0][1] = __builtin_amdgcn_mfma_f32_32x32x16_f16(Ah0, bl1, acc[0][1], 0, 0, 0);
            acc[0][1] = __builtin_amdgcn_mfma_f32_32x32x16_f16(Ah0, bh1, acc[0][1], 0, 0, 0);
            acc[1][0] = __builtin_amdgcn_mfma_f32_32x32x16_f16(Al1, bh0, acc[1][0], 0, 0, 0);
            acc[1][0] = __builtin_amdgcn_mfma_f32_32x32x16_f16(Ah1, bl0, acc[1][0], 0, 0, 0);
            acc[1][0] = __builtin_amdgcn_mfma_f32_32x32x16_f16(Ah1, bh0, acc[1][0], 0, 0, 0);
            acc[1][1] = __builtin_amdgcn_mfma_f32_32x32x16_f16(Al1, bh1, acc[1][1], 0, 0, 0);
            acc[1][1] = __builtin_amdgcn_mfma_f32_32x32x16_f16(Ah1, bl1, acc[1][1], 0, 0, 0);
            acc[1][1] = __builtin_amdgcn_mfma_f32_32x32x16_f16(Ah1, bh1, acc[1][1], 0, 0, 0);
        }
    }
#pragma unroll
    for (int kh = 0; kh < 2; ++kh) {
#pragma unroll
        for (int ls = 0; ls < 2; ++ls) {
            int lcol = l0 + lb0 + ls * 32;
            if (lcol < L_LEN) {
#pragma unroll
                for (int rg = 0; rg < 16; ++rg) {
                    int k = kh * 32 + (rg & 3) + 8 * (rg >> 2) + 4 * kg;
                    h2[((size_t)n * 64 + k) * L_LEN + lcol] = acc[kh][ls][rg];
                }
            }
        }
    }
}

// ---------- sumstat_k: per (n,k) row -> sq (sum of squares), rowsum ----------
__global__ __launch_bounds__(256) void sumstat_k(const float* __restrict__ h2,
                                                 float* __restrict__ sq,
                                                 float* __restrict__ rowsum) {
    int nk = blockIdx.x;
    const float4* row = (const float4*)(h2 + (size_t)nk * L_LEN);
    float s = 0.f, r = 0.f;
    for (int i = threadIdx.x; i < L_LEN / 4; i += 256) {
        float4 v = row[i];
        s += v.x * v.x + v.y * v.y + v.z * v.z + v.w * v.w;
        r += v.x + v.y + v.z + v.w;
    }
#pragma unroll
    for (int off = 32; off; off >>= 1) {
        s += __shfl_down(s, off);
        r += __shfl_down(r, off);
    }
    __shared__ float ss[4], rr[4];
    if ((threadIdx.x & 63) == 0) { ss[threadIdx.x >> 6] = s; rr[threadIdx.x >> 6] = r; }
    __syncthreads();
    if (threadIdx.x == 0) {
        sq[nk] = ss[0] + ss[1] + ss[2] + ss[3];
        rowsum[nk] = rr[0] + rr[1] + rr[2] + rr[3];
    }
}

// ---- corr_k (MFMA): R[a][b][d] = sum_l h2[a][l] * h2[b][l+d-2]  (OOB=0) -----
__global__ __launch_bounds__(256, 3) void corr_k(const float* __restrict__ h2,
                                                 float* __restrict__ Rp) {
    __shared__ __align__(16) unsigned int hl[64 * TW];   // 37,888 B
    int bid = blockIdx.x;
    int xcd = bid & 7;
    int r8 = bid >> 3;            // 0..95
    int n = xcd * 8 + (r8 & 7);   // all 12 splits of n share an XCD
    int s = r8 >> 3;              // 0..11
    const float* h2n = h2 + (size_t)n * 64 * L_LEN;

    int lane = threadIdx.x & 63;
    int wid = threadIdx.x >> 6;
    int a0 = (wid >> 1) * 32;
    int b0 = (wid & 1) * 32;
    int row31 = lane & 31;
    int g = lane >> 5;

    f32x16 acc[5];
#pragma unroll
    for (int d = 0; d < 5; ++d)
#pragma unroll
        for (int i = 0; i < 16; ++i) acc[d][i] = 0.f;

    int trow = threadIdx.x >> 2;   // staging row 0..63
    int tc4 = threadIdx.x & 3;     // staging chunk phase

    const unsigned int* arow = &hl[(a0 + row31) * TW + (g << 3)];
    const unsigned int* brow = &hl[(b0 + row31) * TW + (g << 3)];

    for (int tt = 0; tt < 3; ++tt) {
        int t = s + tt * KSPL;     // tile 0..35
        int l0 = t * KT;
        __syncthreads();           // protect previous tile's readers
        for (int i = 0; i < 9; ++i) {
            int c = tc4 + (i << 2);            // chunk 0..35
            int lbase = l0 - 8 + (c << 2);
            float v[4];
            if (lbase >= 0 && lbase + 3 < L_LEN) {
                float4 f = *(const float4*)(h2n + (size_t)trow * L_LEN + lbase);
                v[0] = f.x; v[1] = f.y; v[2] = f.z; v[3] = f.w;
            } else {
#pragma unroll
                for (int q = 0; q < 4; ++q) {
                    int l = lbase + q;
                    v[q] = (l >= 0 && l < L_LEN) ? h2n[(size_t)trow * L_LEN + l] : 0.f;
                }
            }
            unsigned int wv[4];
#pragma unroll
            for (int q = 0; q < 4; ++q) {
                float xv = v[q];
                _Float16 hi = (_Float16)xv;
                float hif = (float)hi;
                _Float16 lo = (_Float16)(xv - hif);
                unsigned short hb = __builtin_bit_cast(unsigned short, hi);
                unsigned short lb = __builtin_bit_cast(unsigned short, lo);
                wv[q] = (unsigned int)hb | ((unsigned int)lb << 16);
            }
            uint4 uu; uu.x = wv[0]; uu.y = wv[1]; uu.z = wv[2]; uu.w = wv[3];
            *(uint4*)&hl[trow * TW + (c << 2)] = uu;
        }
        __syncthreads();
#pragma unroll
        for (int ks = 0; ks < 8; ++ks) {
            const int u0 = 8 + ks * 16;
            uint4 va0 = *(const uint4*)(arow + u0);
            uint4 va1 = *(const uint4*)(arow + u0 + 4);
            uint4 vb0 = *(const uint4*)(brow + u0 - 4);
            uint4 vb1 = *(const uint4*)(brow + u0);
            uint4 vb2 = *(const uint4*)(brow + u0 + 4);
            uint4 vb3 = *(const uint4*)(brow + u0 + 8);
            unsigned int WA[8] = {va0.x, va0.y, va0.z, va0.w, va1.x, va1.y, va1.z, va1.w};
            unsigned int V[16] = {vb0.x, vb0.y, vb0.z, vb0.w, vb1.x, vb1.y, vb1.z, vb1.w,
                                  vb2.x, vb2.y, vb2.z, vb2.w, vb3.x, vb3.y, vb3.z, vb3.w};
            half8 Ahi = mk_half8(LOPAIR(WA[0], WA[1]), LOPAIR(WA[2], WA[3]),
                                 LOPAIR(WA[4], WA[5]), LOPAIR(WA[6], WA[7]));
            half8 Alo = mk_half8(HIPAIR(WA[0], WA[1]), HIPAIR(WA[2], WA[3]),
                                 HIPAIR(WA[4], WA[5]), HIPAIR(WA[6], WA[7]));
#pragma unroll
            for (int d = 0; d < 5; ++d) {
                half8 Bhi = mk_half8(LOPAIR(V[d + 2], V[d + 3]), LOPAIR(V[d + 4], V[d + 5]),
                                     LOPAIR(V[d + 6], V[d + 7]), LOPAIR(V[d + 8], V[d + 9]));
                half8 Blo = mk_half8(HIPAIR(V[d + 2], V[d + 3]), HIPAIR(V[d + 4], V[d + 5]),
                                     HIPAIR(V[d + 6], V[d + 7]), HIPAIR(V[d + 8], V[d + 9]));
                acc[d] = __builtin_amdgcn_mfma_f32_32x32x16_f16(Alo, Bhi, acc[d], 0, 0, 0);
                acc[d] = __builtin_amdgcn_mfma_f32_32x32x16_f16(Ahi, Blo, acc[d], 0, 0, 0);
                acc[d] = __builtin_amdgcn_mfma_f32_32x32x16_f16(Ahi, Bhi, acc[d], 0, 0, 0);
            }
        }
    }
    float* base = Rp + (size_t)(n * KSPL + s) * 20480;
#pragma unroll
    for (int d = 0; d < 5; ++d) {
#pragma unroll
        for (int rg = 0; rg < 16; ++rg) {
            int crow = (rg & 3) + 8 * (rg >> 2) + 4 * g;
            base[d * 4096 + (a0 + crow) * 64 + b0 + row31] = acc[d][rg];
        }
    }
}

// ---------- reduce_k: element-wise sum of the KSPL partials ------------------
__global__ __launch_bounds__(256) void reduce_k(const float* __restrict__ Rp,
                                                float* __restrict__ Rsum) {
    int n = blockIdx.x / 80;
    int bb = blockIdx.x - n * 80;
    int idx = bb * 256 + threadIdx.x;
    float s = 0.f;
#pragma unroll
    for (int s2 = 0; s2 < KSPL; ++s2) s += Rp[((size_t)n * KSPL + s2) * 20480 + idx];
    Rsum[(size_t)n * 20480 + idx] = s;
}

// ---- mcoef_k: assemble M[c][36] from R + bias/edge terms, then routing ------
__global__ __launch_bounds__(256) void mcoef_k(const float* __restrict__ Rsum,
                                               const float* __restrict__ h2,
                                               const float* __restrict__ sq,
                                               const float* __restrict__ rowsum,
                                               const float* __restrict__ wA,
                                               const float* __restrict__ bA,
                                               float* __restrict__ coefb) {
    __shared__ float Rsub[320];
    __shared__ float Mred[64 * 36];
    __shared__ float s0s[64], s1s[64], Ts[64], invs[64];
    int n = blockIdx.x;
    int c = threadIdx.x & 63;
    int sub = threadIdx.x >> 6;
    if (threadIdx.x < 64) {
        int a = threadIdx.x;
        s0s[a] = h2[((size_t)n * 64 + a) * L_LEN + 0];
        s1s[a] = h2[((size_t)n * 64 + a) * L_LEN + (L_LEN - 1)];
        Ts[a]  = rowsum[n * 64 + a];
        invs[a] = 1.f / (1.f + sq[n * 64 + a]);
    }
    float wreg[24];
#pragma unroll
    for (int q = 0; q < 24; ++q) wreg[q] = wA[c * 24 + q];
    float bc = bA[c];
    __syncthreads();
    float SG[8];
#pragma unroll
    for (int i = 0; i < 8; ++i) {
        float s = 0.f;
#pragma unroll
        for (int p = 0; p < 8; ++p) {
            int a = 8 * i + p;
            float Ta = Ts[a];
            s += invs[a] * (wreg[p * 3 + 0] * (Ta - s1s[a]) +
                            wreg[p * 3 + 1] * Ta +
                            wreg[p * 3 + 2] * (Ta - s0s[a]));
        }
        SG[i] = s;
    }
    float M36[36];
    int ij = 0;
#pragma unroll
    for (int i = 0; i < 8; ++i) {
#pragma unroll
        for (int j = i; j < 8; ++j) {
            __syncthreads();
            for (int fidx = threadIdx.x; fidx < 320; fidx += 256) {
                int p = fidx / 40;
                int r = fidx - 40 * p;
                int pp = r / 5;
                int d = r - 5 * pp;
                int a = 8 * i + p, b = 8 * j + pp;
                Rsub[fidx] = Rsum[(size_t)n * 20480 + d * 4096 + a * 64 + b];
            }
            __syncthreads();
            float acc = 0.f;
#pragma unroll
            for (int pl = 0; pl < 2; ++pl) {
                int p = sub * 2 + pl;
                int a = 8 * i + p;
                float ia = invs[a];
                float w0 = wreg[p * 3], w1 = wreg[p * 3 + 1], w2v = wreg[p * 3 + 2];
                float e1a = s1s[a], e0a = s0s[a];
#pragma unroll
                for (int pp = 0; pp < 8; ++pp) {
                    int b = 8 * j + pp;
                    float q0 = wreg[pp * 3], q1 = wreg[pp * 3 + 1], q2 = wreg[pp * 3 + 2];
                    const float* R5 = &Rsub[(p * 8 + pp) * 5];
                    float term = (w2v * q0) * R5[0]
                               + (w1 * q0 + w2v * q1) * R5[1]
                               + (w0 * q0 + w1 * q1 + w2v * q2) * R5[2]
                               + (w0 * q1 + w1 * q2) * R5[3]
                               + (w0 * q2) * R5[4]
                               - (w0 * q0) * (e1a * s1s[b])
                               - (w2v * q2) * (e0a * s0s[b]);
                    acc += ia * invs[b] * term;
                }
            }
            M36[ij] = acc;
            ++ij;
        }
    }
    __syncthreads();
    if (sub == 0) {
#pragma unroll
        for (int q = 0; q < 36; ++q) Mred[c * 36 + q] = M36[q];
    }
    __syncthreads();
    if (sub == 1) {
#pragma unroll
        for (int q = 0; q < 36; ++q) Mred[c * 36 + q] += M36[q];
    }
    __syncthreads();
    if (sub == 2) {
#pragma unroll
        for (int q = 0; q < 36; ++q) Mred[c * 36 + q] += M36[q];
    }
    __syncthreads();
    if (sub == 3) {
#pragma unroll
        for (int q = 0; q < 36; ++q) Mred[c * 36 + q] += M36[q];
    }
    __syncthreads();
    if (threadIdx.x < 64) {
        float M[36];
        {
            int k2 = 0;
#pragma unroll
            for (int i = 0; i < 8; ++i)
#pragma unroll
                for (int j = i; j < 8; ++j, ++k2)
                    M[k2] = Mred[c * 36 + k2] + bc * (SG[i] + SG[j]) + 4500.f * bc * bc;
        }
        float rs[8];
#pragma unroll
        for (int i = 0; i < 8; ++i) rs[i] = 0.f;
        {
            int idx2 = 0;
#pragma unroll
            for (int i = 0; i < 8; ++i)
#pragma unroll
                for (int j = i; j < 8; ++j, ++idx2) {
                    rs[i] += M[idx2];
                    if (j > i) rs[j] += M[idx2];
                }
        }
        float sumAll = 0.f;
#pragma unroll
        for (int i = 0; i < 8; ++i) sumAll += rs[i];
        float sqn1 = sumAll * (1.f / 64.f);
        float binv = 1.f / (8.f * (1.f + sqn1));
        float bv[8], mx = -1e30f;
#pragma unroll
        for (int i = 0; i < 8; ++i) { bv[i] = rs[i] * binv; mx = fmaxf(mx, bv[i]); }
        float e[8], se = 0.f;
#pragma unroll
        for (int i = 0; i < 8; ++i) { e[i] = expf(bv[i] - mx); se += e[i]; }
        float sinv = 1.f / se;
        float ci_[8];
#pragma unroll
        for (int i = 0; i < 8; ++i) ci_[i] = e[i] * sinv;
        float sqn2 = 0.f;
        {
            int idx2 = 0;
#pragma unroll
            for (int i = 0; i < 8; ++i)
#pragma unroll
                for (int j = i; j < 8; ++j, ++idx2)
                    sqn2 += ((j > i) ? 2.f : 1.f) * ci_[i] * ci_[j] * M[idx2];
        }
        float scale = 1.f / (1.f + sqn2);
#pragma unroll
        for (int i = 0; i < 8; ++i) coefb[((size_t)n * 64 + c) * 8 + i] = ci_[i] * scale;
    }
}

// -------- weff_k: emit Weff directly as MFMA A-fragment hi/lo tables ---------
// Weff[k][ci][g] = coef[n,k,ci>>3]*wA[k,ci&7,g]*inv[n,ci], scaled by 2^16 so
// the f16 hi/lo split stays in the normal range (raw Weff ~4e-6 is subnormal
// and the lo term would underflow). outconv multiplies acc by 2^-16.
__global__ __launch_bounds__(256) void weff_k(const float* __restrict__ coefb,
                                              const float* __restrict__ wA,
                                              const float* __restrict__ sq,
                                              const float* __restrict__ bA,
                                              unsigned int* __restrict__ Wfh,
                                              unsigned int* __restrict__ Wfl,
                                              float* __restrict__ vbias) {
    __shared__ float invs[64];
    __shared__ float coefs[512];
    int n = blockIdx.x;
    if (threadIdx.x < 64) invs[threadIdx.x] = 1.f / (1.f + sq[n * 64 + threadIdx.x]);
    for (int i = threadIdx.x; i < 512; i += 256) coefs[i] = coefb[(size_t)n * 512 + i];
    __syncthreads();
    for (int i = threadIdx.x; i < 6144; i += 256) {
        int w = i & 3;
        int t2 = i >> 2;
        int lane = t2 & 63; t2 >>= 6;
        int ks = t2 & 3; t2 >>= 2;     // t2 now 0..5
        int g = t2 % 3;
        int kh = t2 / 3;
        int k = kh * 32 + (lane & 31);
        int ci0 = ks * 16 + (lane >> 5) * 8 + w * 2;
        unsigned int hw = 0, lw = 0;
#pragma unroll
        for (int e = 0; e < 2; ++e) {
            int ci = ci0 + e;
            float v = coefs[k * 8 + (ci >> 3)] * wA[k * 24 + (ci & 7) * 3 + g] *
                      invs[ci] * 65536.f;
            _Float16 hi = (_Float16)v;
            _Float16 lo = (_Float16)(v - (float)hi);
            unsigned short hb = __builtin_bit_cast(unsigned short, hi);
            unsigned short lb = __builtin_bit_cast(unsigned short, lo);
            hw |= ((unsigned int)hb) << (16 * e);
            lw |= ((unsigned int)lb) << (16 * e);
        }
        Wfh[(size_t)n * 6144 + i] = hw;
        Wfl[(size_t)n * 6144 + i] = lw;
    }
    if (threadIdx.x < 64) {
        float s = 0.f;
#pragma unroll
        for (int i = 0; i < 8; ++i) s += coefb[((size_t)n * 64 + threadIdx.x) * 8 + i];
        vbias[n * 64 + threadIdx.x] = bA[threadIdx.x] * s;
    }
}

// ---- outconv_k (MFMA): out = Weff (64->64, k=3) * h2 + vbias ----------------
__global__ __launch_bounds__(256, 2) void outconv_k(const float* __restrict__ h2,
                                                    const unsigned int* __restrict__ Wfh,
                                                    const unsigned int* __restrict__ Wfl,
                                                    const float* __restrict__ vbias,
                                                    float* __restrict__ out) {
    __shared__ __align__(16) _Float16 shh[258 * RS];
    __shared__ __align__(16) _Float16 shl[258 * RS];
    __shared__ float vbs[64];
    int b = blockIdx.x;
    int xcd = b & 7;
    int gi = xcd * 144 + (b >> 3);
    int n = gi / NTB;
    int t = gi - n * NTB;
    int l0 = t * TL;
    const float* h2n = h2 + (size_t)n * 64 * L_LEN;
    if (threadIdx.x < 64) vbs[threadIdx.x] = vbias[n * 64 + threadIdx.x];
    {
        int ci = threadIdx.x & 63;
        int q = threadIdx.x >> 6;
        int r0 = (q < 2) ? q * 65 : 130 + (q - 2) * 64;
        int cnt = (q < 2) ? 65 : 64;
        const float* hrow = h2n + (size_t)ci * L_LEN;
        for (int tt = 0; tt < cnt; ++tt) {
            int r = r0 + tt;
            int l = l0 - 1 + r;
            float a = (l >= 0 && l < L_LEN) ? hrow[l] : 0.f;
            _Float16 hi = (_Float16)a;
            _Float16 lo = (_Float16)(a - (float)hi);
            shh[r * RS + ci] = hi;
            shl[r * RS + ci] = lo;
        }
    }
    __syncthreads();
    int lane = threadIdx.x & 63;
    int wid = threadIdx.x >> 6;
    int col = lane & 31;
    int kg = lane >> 5;
    int lb0 = wid * 64 + col;
    f32x16 acc[2][2];
#pragma unroll
    for (int a1 = 0; a1 < 2; ++a1)
#pragma unroll
        for (int a2 = 0; a2 < 2; ++a2)
#pragma unroll
            for (int i = 0; i < 16; ++i) acc[a1][a2][i] = 0.f;
    const uint4* WH = (const uint4*)(Wfh + (size_t)n * 6144);
    const uint4* WL = (const uint4*)(Wfl + (size_t)n * 6144);
#pragma unroll
    for (int g = 0; g < 3; ++g) {
#pragma unroll
        for (int ks = 0; ks < 4; ++ks) {
            uint4 ah0 = WH[((0 * 3 + g) * 4 + ks) * 64 + lane];
            uint4 ah1 = WH[((1 * 3 + g) * 4 + ks) * 64 + lane];
            uint4 al0 = WL[((0 * 3 + g) * 4 + ks) * 64 + lane];
            uint4 al1 = WL[((1 * 3 + g) * 4 + ks) * 64 + lane];
            int off = ks * 16 + kg * 8;
            half8 bh0 = *(const half8*)&shh[(lb0 + g) * RS + off];
            half8 bl0 = *(const half8*)&shl[(lb0 + g) * RS + off];
            half8 bh1 = *(const half8*)&shh[(lb0 + 32 + g) * RS + off];
            half8 bl1 = *(const half8*)&shl[(lb0 + 32 + g) * RS + off];
            half8 Ah0 = u4_half8(ah0), Al0 = u4_half8(al0);
            half8 Ah1 = u4_half8(ah1), Al1 = u4_half8(al1);
            acc[0][0] = __builtin_amdgcn_mfma_f32_32x32x16_f16(Al0, bh0, acc[0][0], 0, 0, 0);
            acc[0][0] = __builtin_amdgcn_mfma_f32_32x32x16_f16(Ah0, bl0, acc[0][0], 0, 0, 0);
            acc[0][0] = __builtin_amdgcn_mfma_f32_32x32x16_f16(Ah0, bh0, acc[0][0], 0, 0, 0);
            acc[0][1] = __builtin_amdgcn_mfma_f32_32x32x16_f16(Al0, bh1, acc[0][1], 0, 0, 0);
            acc[0][1] = __builtin_amdgcn_mfma_f32_32x32x16_f16(Ah0, bl1, acc[0][1], 0, 0, 0);
            acc[0][1] = __builtin_amdgcn_mfma_f32_32x32x16_f16(Ah0, bh1, acc[0][1], 0, 0, 0);
            acc[1][0] = __builtin_amdgcn_mfma_f32_32x32x16_f16(Al1, bh0, acc[1][0], 0, 0, 0);
            acc[1][0] = __builtin_amdgcn_mfma_f32_32x32x16_f16(Ah1, bl0, acc[1][0], 0, 0, 0);
            acc[1][0] = __builtin_amdgcn_mfma_f32_32x32x16_f16(Ah1, bh0, acc[1][0], 0, 0, 0);
            acc[1][1] = __builtin_amdgcn_mfma_f32_32x32x16_f16(Al1, bh1, acc[1][1], 0, 0, 0);
            acc[1][1] = __builtin_amdgcn_mfma_f32_32x32x16_f16(Ah1, bl1, acc[1][1], 0, 0, 0);
            acc[1][1] = __builtin_amdgcn_mfma_f32_32x32x16_f16(Ah1, bh1, acc[1][1], 0, 0, 0);
        }
    }
    const float inv_scale = 1.f / 65536.f;
#pragma unroll
    for (int kh = 0; kh < 2; ++kh) {
#pragma unroll
        for (int ls = 0; ls < 2; ++ls) {
            int lcol = l0 + lb0 + ls * 32;
            if (lcol < L_LEN) {
#pragma unroll
                for (int rg = 0; rg < 16; ++rg) {
                    int k = kh * 32 + (rg & 3) + 8 * (rg >> 2) + 4 * kg;
                    out[((size_t)n * 64 + k) * L_LEN + lcol] =
                        acc[kh][ls][rg] * inv_scale + vbs[k];
                }
            }
        }
    }
}

extern "C" void kernel_launch(void* const* d_in, const int* in_sizes, int n_in,
                              void* d_out, int out_size, void* d_ws, size_t ws_size,
                              hipStream_t stream) {
    const float* x  = (const float*)d_in[0];
    const float* w1 = (const float*)d_in[1];
    const float* w2 = (const float*)d_in[2];
    const float* wA = (const float*)d_in[3];
    const float* bA = (const float*)d_in[4];
    float* out = (float*)d_out;
    char* ws = (char*)d_ws;
    const size_t HB = (size_t)64 * 64 * L_LEN * 4;   // 73,728,000 B
    float* h2     = (float*)(ws + HB);
    float* sq     = (float*)(ws + 2 * HB);            // 16 KB
    float* rowsum = (float*)(ws + 2 * HB + 16384);    // 16 KB
    unsigned int* w2fh = (unsigned int*)(ws + 2 * HB + 32768);   // 40 KB
    unsigned int* w2fl = (unsigned int*)(ws + 2 * HB + 32768 + 40960); // 40 KB
    // overlays in the first HB region:
    float* Rp    = (float*)ws;                        // 62,914,560 B
    float* Rsum  = (float*)(ws + 62914560);           //  5,242,880 B
    float* coefb = (float*)(ws + 68157440);           //    131,072 B
    unsigned int* Wfh = (unsigned int*)(ws + 68288512);           // 1,572,864 B
    unsigned int* Wfl = (unsigned int*)(ws + 68288512 + 1572864); // 1,572,864 B
    float* vbias = (float*)(ws + 71434240);           //     16,384 B

    prep_w2f_k<<<40, 256, 0, stream>>>(w2, w2fh, w2fl);
    conv12_k<<<64 * NTB, 256, 0, stream>>>(x, w1, w2fh, w2fl, h2);
    sumstat_k<<<4096, 256, 0, stream>>>(h2, sq, rowsum);
    corr_k<<<64 * KSPL, 256, 0, stream>>>(h2, Rp);
    reduce_k<<<64 * 80, 256, 0, stream>>>(Rp, Rsum);
    mcoef_k<<<64, 256, 0, stream>>>(Rsum, h2, sq, rowsum, wA, bA, coefb);
    weff_k<<<64, 256, 0, stream>>>(coefb, wA, sq, bA, Wfh, Wfl, vbias);
    outconv_k<<<64 * NTB, 256, 0, stream>>>(h2, Wfh, Wfl, vbias, out);
}

// Round 3
// 392.042 us; speedup vs baseline: 1.5651x; 1.0526x over previous
//
#include <hip/hip_runtime.h>
#include <math.h>

#define L_LEN 4500
#define KSPL 12   // K-splits for corr_k
#define KT 128    // corr K-tile (elements)
#define TW 148    // corr LDS row stride in words
#define TL 256    // conv l-tile
#define NTB 18    // ceil(4500/256)
#define RS 72     // conv LDS plane row stride (f16 units); 16B-chunk stride 9 (odd) -> conflict-free b128

typedef _Float16 half8 __attribute__((ext_vector_type(8)));
typedef float f32x16 __attribute__((ext_vector_type(16)));

__device__ __forceinline__ half8 mk_half8(unsigned int w0, unsigned int w1,
                                          unsigned int w2, unsigned int w3) {
    union { unsigned int u[4]; half8 h; } t;
    t.u[0] = w0; t.u[1] = w1; t.u[2] = w2; t.u[3] = w3;
    return t.h;
}
__device__ __forceinline__ half8 u4_half8(uint4 v) {
    union { uint4 u; half8 h; } t; t.u = v; return t.h;
}

#define LOPAIR(a, b) (((a) & 0xffffu) | ((b) << 16))
#define HIPAIR(a, b) (((a) >> 16) | ((b) & 0xffff0000u))

// ------- prep: pack conv2 weights into MFMA A-fragment hi/lo u32 tables ------
// Also zero-inits sq/rowsum (conv12 now accumulates them atomically).
__global__ void prep_w2f_k(const float* __restrict__ w2,
                           unsigned int* __restrict__ w2fh,
                           unsigned int* __restrict__ w2fl,
                           float* __restrict__ sq,
                           float* __restrict__ rowsum) {
    int i = blockIdx.x * 256 + threadIdx.x;
    if (i < 4096) { sq[i] = 0.f; rowsum[i] = 0.f; }
    if (i >= 10240) return;
    int w = i & 3;
    int t = i >> 2;
    int lane = t & 63; t >>= 6;
    int ks = t & 3; t >>= 2;          // t now 0..9
    int g = t % 5;
    int kh = t / 5;
    int k = kh * 32 + (lane & 31);
    int ci0 = ks * 16 + (lane >> 5) * 8 + w * 2;
    unsigned int hw = 0, lw = 0;
#pragma unroll
    for (int e = 0; e < 2; ++e) {
        float v = w2[(k * 64 + ci0 + e) * 5 + g];
        _Float16 hi = (_Float16)v;
        _Float16 lo = (_Float16)(v - (float)hi);
        unsigned short hb = __builtin_bit_cast(unsigned short, hi);
        unsigned short lb = __builtin_bit_cast(unsigned short, lo);
        hw |= ((unsigned int)hb) << (16 * e);
        lw |= ((unsigned int)lb) << (16 * e);
    }
    w2fh[i] = hw;
    w2fl[i] = lw;
}

// ---- conv12_k (MFMA): fused conv1(k=7) + conv2(k=5), f16 hi/lo 3-split ------
// Epilogue now also reduces sq/rowsum from the in-register h2 values
// (32-lane shfl_xor per half-wave + one atomicAdd per (n,k) per block),
// replacing the sumstat kernel's full 74 MB re-read of h2.
__global__ __launch_bounds__(256, 2) void conv12_k(const float* __restrict__ x,
                                                   const float* __restrict__ w1,
                                                   const unsigned int* __restrict__ w2fh,
                                                   const unsigned int* __restrict__ w2fl,
                                                   float* __restrict__ h2,
                                                   float* __restrict__ sq,
                                                   float* __restrict__ rowsum) {
    __shared__ float xs[268];
    __shared__ __align__(16) _Float16 shh[260 * RS];
    __shared__ __align__(16) _Float16 shl[260 * RS];
    int b = blockIdx.x;
    int xcd = b & 7;
    int gi = xcd * 144 + (b >> 3);
    int n = gi / NTB;
    int t = gi - n * NTB;
    int l0 = t * TL;
    const float* xr = x + (size_t)n * L_LEN;
    for (int idx = threadIdx.x; idx < 266; idx += 256) {
        int l = l0 - 5 + idx;
        xs[idx] = (l >= 0 && l < L_LEN) ? xr[l] : 0.f;
    }
    __syncthreads();
    {
        int ci = threadIdx.x & 63;
        int q = threadIdx.x >> 6;
        float w[7];
#pragma unroll
        for (int g = 0; g < 7; ++g) w[g] = w1[ci * 7 + g];
        for (int tt = 0; tt < 65; ++tt) {
            int r = q * 65 + tt;
            int l = l0 + r - 2;
            float a = 0.f;
            if (l >= 0 && l < L_LEN) {
#pragma unroll
                for (int g = 0; g < 7; ++g) a += w[g] * xs[r + g];
            }
            _Float16 hi = (_Float16)a;
            _Float16 lo = (_Float16)(a - (float)hi);
            shh[r * RS + ci] = hi;
            shl[r * RS + ci] = lo;
        }
    }
    __syncthreads();
    int lane = threadIdx.x & 63;
    int wid = threadIdx.x >> 6;
    int col = lane & 31;
    int kg = lane >> 5;
    int lb0 = wid * 64 + col;
    f32x16 acc[2][2];
#pragma unroll
    for (int a1 = 0; a1 < 2; ++a1)
#pragma unroll
        for (int a2 = 0; a2 < 2; ++a2)
#pragma unroll
            for (int i = 0; i < 16; ++i) acc[a1][a2][i] = 0.f;
    const uint4* WH = (const uint4*)w2fh;
    const uint4* WL = (const uint4*)w2fl;
#pragma unroll
    for (int g = 0; g < 5; ++g) {
#pragma unroll
        for (int ks = 0; ks < 4; ++ks) {
            uint4 ah0 = WH[((0 * 5 + g) * 4 + ks) * 64 + lane];
            uint4 ah1 = WH[((1 * 5 + g) * 4 + ks) * 64 + lane];
            uint4 al0 = WL[((0 * 5 + g) * 4 + ks) * 64 + lane];
            uint4 al1 = WL[((1 * 5 + g) * 4 + ks) * 64 + lane];
            int off = ks * 16 + kg * 8;
            half8 bh0 = *(const half8*)&shh[(lb0 + g) * RS + off];
            half8 bl0 = *(const half8*)&shl[(lb0 + g) * RS + off];
            half8 bh1 = *(const half8*)&shh[(lb0 + 32 + g) * RS + off];
            half8 bl1 = *(const half8*)&shl[(lb0 + 32 + g) * RS + off];
            half8 Ah0 = u4_half8(ah0), Al0 = u4_half8(al0);
            half8 Ah1 = u4_half8(ah1), Al1 = u4_half8(al1);
            acc[0][0] = __builtin_amdgcn_mfma_f32_32x32x16_f16(Al0, bh0, acc[0][0], 0, 0, 0);
            acc[0][0] = __builtin_amdgcn_mfma_f32_32x32x16_f16(Ah0, bl0, acc[0][0], 0, 0, 0);
            acc[0][0] = __builtin_amdgcn_mfma_f32_32x32x16_f16(Ah0, bh0, acc[0][0], 0, 0, 0);
            acc[0][1] = __builtin_amdgcn_mfma_f32_32x32x16_f16(Al0, bh1, acc[0][1], 0, 0, 0);
            acc[0][1] = __builtin_amdgcn_mfma_f32_32x32x16_f16(Ah0, bl1, acc[0][1], 0, 0, 0);
            acc[0][1] = __builtin_amdgcn_mfma_f32_32x32x16_f16(Ah0, bh1, acc[0][1], 0, 0, 0);
            acc[1][0] = __builtin_amdgcn_mfma_f32_32x32x16_f16(Al1, bh0, acc[1][0], 0, 0, 0);
            acc[1][0] = __builtin_amdgcn_mfma_f32_32x32x16_f16(Ah1, bl0, acc[1][0], 0, 0, 0);
            acc[1][0] = __builtin_amdgcn_mfma_f32_32x32x16_f16(Ah1, bh0, acc[1][0], 0, 0, 0);
            acc[1][1] = __builtin_amdgcn_mfma_f32_32x32x16_f16(Al1, bh1, acc[1][1], 0, 0, 0);
            acc[1][1] = __builtin_amdgcn_mfma_f32_32x32x16_f16(Ah1, bl1, acc[1][1], 0, 0, 0);
            acc[1][1] = __builtin_amdgcn_mfma_f32_32x32x16_f16(Ah1, bh1, acc[1][1], 0, 0, 0);
        }
    }
#pragma unroll
    for (int kh = 0; kh < 2; ++kh) {
#pragma unroll
        for (int ls = 0; ls < 2; ++ls) {
            int lcol = l0 + lb0 + ls * 32;
            if (lcol < L_LEN) {
#pragma unroll
                for (int rg = 0; rg < 16; ++rg) {
                    int k = kh * 32 + (rg & 3) + 8 * (rg >> 2) + 4 * kg;
                    h2[((size_t)n * 64 + k) * L_LEN + lcol] = acc[kh][ls][rg];
                }
            }
        }
    }
    // ---- fused sumstat: per (kh,rg) reduce this wave's 64 l-cols ----
#pragma unroll
    for (int kh = 0; kh < 2; ++kh) {
#pragma unroll
        for (int rg = 0; rg < 16; ++rg) {
            float s1 = 0.f, s2 = 0.f;
#pragma unroll
            for (int ls = 0; ls < 2; ++ls) {
                int lcol = l0 + lb0 + ls * 32;
                if (lcol < L_LEN) {
                    float v = acc[kh][ls][rg];
                    s1 += v; s2 += v * v;
                }
            }
#pragma unroll
            for (int m = 16; m; m >>= 1) {
                s1 += __shfl_xor(s1, m, 32);
                s2 += __shfl_xor(s2, m, 32);
            }
            if (col == 0) {
                int k = kh * 32 + (rg & 3) + 8 * (rg >> 2) + 4 * kg;
                atomicAdd(&rowsum[n * 64 + k], s1);
                atomicAdd(&sq[n * 64 + k], s2);
            }
        }
    }
}

// ---- corr_k (MFMA): R[a][b][d] = sum_l h2[a][l] * h2[b][l+d-2]  (OOB=0) -----
__global__ __launch_bounds__(256, 3) void corr_k(const float* __restrict__ h2,
                                                 float* __restrict__ Rp) {
    __shared__ __align__(16) unsigned int hl[64 * TW];   // 37,888 B
    int bid = blockIdx.x;
    int xcd = bid & 7;
    int r8 = bid >> 3;            // 0..95
    int n = xcd * 8 + (r8 & 7);   // all 12 splits of n share an XCD
    int s = r8 >> 3;              // 0..11
    const float* h2n = h2 + (size_t)n * 64 * L_LEN;

    int lane = threadIdx.x & 63;
    int wid = threadIdx.x >> 6;
    int a0 = (wid >> 1) * 32;
    int b0 = (wid & 1) * 32;
    int row31 = lane & 31;
    int g = lane >> 5;

    f32x16 acc[5];
#pragma unroll
    for (int d = 0; d < 5; ++d)
#pragma unroll
        for (int i = 0; i < 16; ++i) acc[d][i] = 0.f;

    int trow = threadIdx.x >> 2;   // staging row 0..63
    int tc4 = threadIdx.x & 3;     // staging chunk phase

    const unsigned int* arow = &hl[(a0 + row31) * TW + (g << 3)];
    const unsigned int* brow = &hl[(b0 + row31) * TW + (g << 3)];

    for (int tt = 0; tt < 3; ++tt) {
        int t = s + tt * KSPL;     // tile 0..35
        int l0 = t * KT;
        __syncthreads();           // protect previous tile's readers
        for (int i = 0; i < 9; ++i) {
            int c = tc4 + (i << 2);            // chunk 0..35
            int lbase = l0 - 8 + (c << 2);
            float v[4];
            if (lbase >= 0 && lbase + 3 < L_LEN) {
                float4 f = *(const float4*)(h2n + (size_t)trow * L_LEN + lbase);
                v[0] = f.x; v[1] = f.y; v[2] = f.z; v[3] = f.w;
            } else {
#pragma unroll
                for (int q = 0; q < 4; ++q) {
                    int l = lbase + q;
                    v[q] = (l >= 0 && l < L_LEN) ? h2n[(size_t)trow * L_LEN + l] : 0.f;
                }
            }
            unsigned int wv[4];
#pragma unroll
            for (int q = 0; q < 4; ++q) {
                float xv = v[q];
                _Float16 hi = (_Float16)xv;
                float hif = (float)hi;
                _Float16 lo = (_Float16)(xv - hif);
                unsigned short hb = __builtin_bit_cast(unsigned short, hi);
                unsigned short lb = __builtin_bit_cast(unsigned short, lo);
                wv[q] = (unsigned int)hb | ((unsigned int)lb << 16);
            }
            uint4 uu; uu.x = wv[0]; uu.y = wv[1]; uu.z = wv[2]; uu.w = wv[3];
            *(uint4*)&hl[trow * TW + (c << 2)] = uu;
        }
        __syncthreads();
#pragma unroll
        for (int ks = 0; ks < 8; ++ks) {
            const int u0 = 8 + ks * 16;
            uint4 va0 = *(const uint4*)(arow + u0);
            uint4 va1 = *(const uint4*)(arow + u0 + 4);
            uint4 vb0 = *(const uint4*)(brow + u0 - 4);
            uint4 vb1 = *(const uint4*)(brow + u0);
            uint4 vb2 = *(const uint4*)(brow + u0 + 4);
            uint4 vb3 = *(const uint4*)(brow + u0 + 8);
            unsigned int WA[8] = {va0.x, va0.y, va0.z, va0.w, va1.x, va1.y, va1.z, va1.w};
            unsigned int V[16] = {vb0.x, vb0.y, vb0.z, vb0.w, vb1.x, vb1.y, vb1.z, vb1.w,
                                  vb2.x, vb2.y, vb2.z, vb2.w, vb3.x, vb3.y, vb3.z, vb3.w};
            half8 Ahi = mk_half8(LOPAIR(WA[0], WA[1]), LOPAIR(WA[2], WA[3]),
                                 LOPAIR(WA[4], WA[5]), LOPAIR(WA[6], WA[7]));
            half8 Alo = mk_half8(HIPAIR(WA[0], WA[1]), HIPAIR(WA[2], WA[3]),
                                 HIPAIR(WA[4], WA[5]), HIPAIR(WA[6], WA[7]));
#pragma unroll
            for (int d = 0; d < 5; ++d) {
                half8 Bhi = mk_half8(LOPAIR(V[d + 2], V[d + 3]), LOPAIR(V[d + 4], V[d + 5]),
                                     LOPAIR(V[d + 6], V[d + 7]), LOPAIR(V[d + 8], V[d + 9]));
                half8 Blo = mk_half8(HIPAIR(V[d + 2], V[d + 3]), HIPAIR(V[d + 4], V[d + 5]),
                                     HIPAIR(V[d + 6], V[d + 7]), HIPAIR(V[d + 8], V[d + 9]));
                acc[d] = __builtin_amdgcn_mfma_f32_32x32x16_f16(Alo, Bhi, acc[d], 0, 0, 0);
                acc[d] = __builtin_amdgcn_mfma_f32_32x32x16_f16(Ahi, Blo, acc[d], 0, 0, 0);
                acc[d] = __builtin_amdgcn_mfma_f32_32x32x16_f16(Ahi, Bhi, acc[d], 0, 0, 0);
            }
        }
    }
    float* base = Rp + (size_t)(n * KSPL + s) * 20480;
#pragma unroll
    for (int d = 0; d < 5; ++d) {
#pragma unroll
        for (int rg = 0; rg < 16; ++rg) {
            int crow = (rg & 3) + 8 * (rg >> 2) + 4 * g;
            base[d * 4096 + (a0 + crow) * 64 + b0 + row31] = acc[d][rg];
        }
    }
}

// ---------- reduce_k: element-wise sum of the KSPL partials ------------------
__global__ __launch_bounds__(256) void reduce_k(const float* __restrict__ Rp,
                                                float* __restrict__ Rsum) {
    int n = blockIdx.x / 80;
    int bb = blockIdx.x - n * 80;
    int idx = bb * 256 + threadIdx.x;
    float s = 0.f;
#pragma unroll
    for (int s2 = 0; s2 < KSPL; ++s2) s += Rp[((size_t)n * KSPL + s2) * 20480 + idx];
    Rsum[(size_t)n * 20480 + idx] = s;
}

// ---- mcoef_k: assemble M[c][36] from R + bias/edge terms, then routing ------
__global__ __launch_bounds__(256) void mcoef_k(const float* __restrict__ Rsum,
                                               const float* __restrict__ h2,
                                               const float* __restrict__ sq,
                                               const float* __restrict__ rowsum,
                                               const float* __restrict__ wA,
                                               const float* __restrict__ bA,
                                               float* __restrict__ coefb) {
    __shared__ float Rsub[320];
    __shared__ float Mred[64 * 36];
    __shared__ float s0s[64], s1s[64], Ts[64], invs[64];
    int n = blockIdx.x;
    int c = threadIdx.x & 63;
    int sub = threadIdx.x >> 6;
    if (threadIdx.x < 64) {
        int a = threadIdx.x;
        s0s[a] = h2[((size_t)n * 64 + a) * L_LEN + 0];
        s1s[a] = h2[((size_t)n * 64 + a) * L_LEN + (L_LEN - 1)];
        Ts[a]  = rowsum[n * 64 + a];
        invs[a] = 1.f / (1.f + sq[n * 64 + a]);
    }
    float wreg[24];
#pragma unroll
    for (int q = 0; q < 24; ++q) wreg[q] = wA[c * 24 + q];
    float bc = bA[c];
    __syncthreads();
    float SG[8];
#pragma unroll
    for (int i = 0; i < 8; ++i) {
        float s = 0.f;
#pragma unroll
        for (int p = 0; p < 8; ++p) {
            int a = 8 * i + p;
            float Ta = Ts[a];
            s += invs[a] * (wreg[p * 3 + 0] * (Ta - s1s[a]) +
                            wreg[p * 3 + 1] * Ta +
                            wreg[p * 3 + 2] * (Ta - s0s[a]));
        }
        SG[i] = s;
    }
    float M36[36];
    int ij = 0;
#pragma unroll
    for (int i = 0; i < 8; ++i) {
#pragma unroll
        for (int j = i; j < 8; ++j) {
            __syncthreads();
            for (int fidx = threadIdx.x; fidx < 320; fidx += 256) {
                int p = fidx / 40;
                int r = fidx - 40 * p;
                int pp = r / 5;
                int d = r - 5 * pp;
                int a = 8 * i + p, b = 8 * j + pp;
                Rsub[fidx] = Rsum[(size_t)n * 20480 + d * 4096 + a * 64 + b];
            }
            __syncthreads();
            float acc = 0.f;
#pragma unroll
            for (int pl = 0; pl < 2; ++pl) {
                int p = sub * 2 + pl;
                int a = 8 * i + p;
                float ia = invs[a];
                float w0 = wreg[p * 3], w1 = wreg[p * 3 + 1], w2v = wreg[p * 3 + 2];
                float e1a = s1s[a], e0a = s0s[a];
#pragma unroll
                for (int pp = 0; pp < 8; ++pp) {
                    int b = 8 * j + pp;
                    float q0 = wreg[pp * 3], q1 = wreg[pp * 3 + 1], q2 = wreg[pp * 3 + 2];
                    const float* R5 = &Rsub[(p * 8 + pp) * 5];
                    float term = (w2v * q0) * R5[0]
                               + (w1 * q0 + w2v * q1) * R5[1]
                               + (w0 * q0 + w1 * q1 + w2v * q2) * R5[2]
                               + (w0 * q1 + w1 * q2) * R5[3]
                               + (w0 * q2) * R5[4]
                               - (w0 * q0) * (e1a * s1s[b])
                               - (w2v * q2) * (e0a * s0s[b]);
                    acc += ia * invs[b] * term;
                }
            }
            M36[ij] = acc;
            ++ij;
        }
    }
    __syncthreads();
    if (sub == 0) {
#pragma unroll
        for (int q = 0; q < 36; ++q) Mred[c * 36 + q] = M36[q];
    }
    __syncthreads();
    if (sub == 1) {
#pragma unroll
        for (int q = 0; q < 36; ++q) Mred[c * 36 + q] += M36[q];
    }
    __syncthreads();
    if (sub == 2) {
#pragma unroll
        for (int q = 0; q < 36; ++q) Mred[c * 36 + q] += M36[q];
    }
    __syncthreads();
    if (sub == 3) {
#pragma unroll
        for (int q = 0; q < 36; ++q) Mred[c * 36 + q] += M36[q];
    }
    __syncthreads();
    if (threadIdx.x < 64) {
        float M[36];
        {
            int k2 = 0;
#pragma unroll
            for (int i = 0; i < 8; ++i)
#pragma unroll
                for (int j = i; j < 8; ++j, ++k2)
                    M[k2] = Mred[c * 36 + k2] + bc * (SG[i] + SG[j]) + 4500.f * bc * bc;
        }
        float rs[8];
#pragma unroll
        for (int i = 0; i < 8; ++i) rs[i] = 0.f;
        {
            int idx2 = 0;
#pragma unroll
            for (int i = 0; i < 8; ++i)
#pragma unroll
                for (int j = i; j < 8; ++j, ++idx2) {
                    rs[i] += M[idx2];
                    if (j > i) rs[j] += M[idx2];
                }
        }
        float sumAll = 0.f;
#pragma unroll
        for (int i = 0; i < 8; ++i) sumAll += rs[i];
        float sqn1 = sumAll * (1.f / 64.f);
        float binv = 1.f / (8.f * (1.f + sqn1));
        float bv[8], mx = -1e30f;
#pragma unroll
        for (int i = 0; i < 8; ++i) { bv[i] = rs[i] * binv; mx = fmaxf(mx, bv[i]); }
        float e[8], se = 0.f;
#pragma unroll
        for (int i = 0; i < 8; ++i) { e[i] = expf(bv[i] - mx); se += e[i]; }
        float sinv = 1.f / se;
        float ci_[8];
#pragma unroll
        for (int i = 0; i < 8; ++i) ci_[i] = e[i] * sinv;
        float sqn2 = 0.f;
        {
            int idx2 = 0;
#pragma unroll
            for (int i = 0; i < 8; ++i)
#pragma unroll
                for (int j = i; j < 8; ++j, ++idx2)
                    sqn2 += ((j > i) ? 2.f : 1.f) * ci_[i] * ci_[j] * M[idx2];
        }
        float scale = 1.f / (1.f + sqn2);
#pragma unroll
        for (int i = 0; i < 8; ++i) coefb[((size_t)n * 64 + c) * 8 + i] = ci_[i] * scale;
    }
}

// -------- weff_k: emit Weff directly as MFMA A-fragment hi/lo tables ---------
__global__ __launch_bounds__(256) void weff_k(const float* __restrict__ coefb,
                                              const float* __restrict__ wA,
                                              const float* __restrict__ sq,
                                              const float* __restrict__ bA,
                                              unsigned int* __restrict__ Wfh,
                                              unsigned int* __restrict__ Wfl,
                                              float* __restrict__ vbias) {
    __shared__ float invs[64];
    __shared__ float coefs[512];
    int n = blockIdx.x;
    if (threadIdx.x < 64) invs[threadIdx.x] = 1.f / (1.f + sq[n * 64 + threadIdx.x]);
    for (int i = threadIdx.x; i < 512; i += 256) coefs[i] = coefb[(size_t)n * 512 + i];
    __syncthreads();
    for (int i = threadIdx.x; i < 6144; i += 256) {
        int w = i & 3;
        int t2 = i >> 2;
        int lane = t2 & 63; t2 >>= 6;
        int ks = t2 & 3; t2 >>= 2;     // t2 now 0..5
        int g = t2 % 3;
        int kh = t2 / 3;
        int k = kh * 32 + (lane & 31);
        int ci0 = ks * 16 + (lane >> 5) * 8 + w * 2;
        unsigned int hw = 0, lw = 0;
#pragma unroll
        for (int e = 0; e < 2; ++e) {
            int ci = ci0 + e;
            float v = coefs[k * 8 + (ci >> 3)] * wA[k * 24 + (ci & 7) * 3 + g] *
                      invs[ci] * 65536.f;
            _Float16 hi = (_Float16)v;
            _Float16 lo = (_Float16)(v - (float)hi);
            unsigned short hb = __builtin_bit_cast(unsigned short, hi);
            unsigned short lb = __builtin_bit_cast(unsigned short, lo);
            hw |= ((unsigned int)hb) << (16 * e);
            lw |= ((unsigned int)lb) << (16 * e);
        }
        Wfh[(size_t)n * 6144 + i] = hw;
        Wfl[(size_t)n * 6144 + i] = lw;
    }
    if (threadIdx.x < 64) {
        float s = 0.f;
#pragma unroll
        for (int i = 0; i < 8; ++i) s += coefb[((size_t)n * 64 + threadIdx.x) * 8 + i];
        vbias[n * 64 + threadIdx.x] = bA[threadIdx.x] * s;
    }
}

// ---- outconv_k (MFMA): out = Weff (64->64, k=3) * h2 + vbias ----------------
// Staging rewritten: coalesced float4 reads of h2 (4 lanes/row x 16 rows/wave,
// ~17 independent vector loads per thread) + transposed b16 LDS writes.
// LDS rows r' = l - (l0-4), staged r' in [0,264); compute reads rows
// lb0 + g + 3 (+32). Replaces the 65-scalar-uncoalesced-gather staging that
// made this kernel latency-bound (120us, all pipes <8%).
__global__ __launch_bounds__(256, 2) void outconv_k(const float* __restrict__ h2,
                                                    const unsigned int* __restrict__ Wfh,
                                                    const unsigned int* __restrict__ Wfl,
                                                    const float* __restrict__ vbias,
                                                    float* __restrict__ out) {
    __shared__ __align__(16) _Float16 shh[264 * RS];
    __shared__ __align__(16) _Float16 shl[264 * RS];
    __shared__ float vbs[64];
    int b = blockIdx.x;
    int xcd = b & 7;
    int gi = xcd * 144 + (b >> 3);
    int n = gi / NTB;
    int t = gi - n * NTB;
    int l0 = t * TL;
    const float* h2n = h2 + (size_t)n * 64 * L_LEN;
    if (threadIdx.x < 64) vbs[threadIdx.x] = vbias[n * 64 + threadIdx.x];
    {
        int trow = threadIdx.x >> 2;       // h2 row (ci) 0..63
        int tc4 = threadIdx.x & 3;         // chunk phase
        const float* hrow = h2n + (size_t)trow * L_LEN;
        int lb = l0 - 4;
        for (int i = 0; i < 17; ++i) {
            int c = tc4 + 4 * i;
            if (c >= 66) break;
            int lbase = lb + 4 * c;
            float v[4];
            if (lbase >= 0 && lbase + 3 < L_LEN) {
                float4 f = *(const float4*)(hrow + lbase);
                v[0] = f.x; v[1] = f.y; v[2] = f.z; v[3] = f.w;
            } else {
#pragma unroll
                for (int q = 0; q < 4; ++q) {
                    int l = lbase + q;
                    v[q] = (l >= 0 && l < L_LEN) ? hrow[l] : 0.f;
                }
            }
            int r = 4 * c;
#pragma unroll
            for (int q = 0; q < 4; ++q) {
                _Float16 hi = (_Float16)v[q];
                _Float16 lo = (_Float16)(v[q] - (float)hi);
                shh[(r + q) * RS + trow] = hi;
                shl[(r + q) * RS + trow] = lo;
            }
        }
    }
    __syncthreads();
    int lane = threadIdx.x & 63;
    int wid = threadIdx.x >> 6;
    int col = lane & 31;
    int kg = lane >> 5;
    int lb0 = wid * 64 + col;
    f32x16 acc[2][2];
#pragma unroll
    for (int a1 = 0; a1 < 2; ++a1)
#pragma unroll
        for (int a2 = 0; a2 < 2; ++a2)
#pragma unroll
            for (int i = 0; i < 16; ++i) acc[a1][a2][i] = 0.f;
    const uint4* WH = (const uint4*)(Wfh + (size_t)n * 6144);
    const uint4* WL = (const uint4*)(Wfl + (size_t)n * 6144);
#pragma unroll
    for (int g = 0; g < 3; ++g) {
#pragma unroll
        for (int ks = 0; ks < 4; ++ks) {
            uint4 ah0 = WH[((0 * 3 + g) * 4 + ks) * 64 + lane];
            uint4 ah1 = WH[((1 * 3 + g) * 4 + ks) * 64 + lane];
            uint4 al0 = WL[((0 * 3 + g) * 4 + ks) * 64 + lane];
            uint4 al1 = WL[((1 * 3 + g) * 4 + ks) * 64 + lane];
            int off = ks * 16 + kg * 8;
            int rb = lb0 + g + 3;
            half8 bh0 = *(const half8*)&shh[rb * RS + off];
            half8 bl0 = *(const half8*)&shl[rb * RS + off];
            half8 bh1 = *(const half8*)&shh[(rb + 32) * RS + off];
            half8 bl1 = *(const half8*)&shl[(rb + 32) * RS + off];
            half8 Ah0 = u4_half8(ah0), Al0 = u4_half8(al0);
            half8 Ah1 = u4_half8(ah1), Al1 = u4_half8(al1);
            acc[0][0] = __builtin_amdgcn_mfma_f32_32x32x16_f16(Al0, bh0, acc[0][0], 0, 0, 0);
            acc[0][0] = __builtin_amdgcn_mfma_f32_32x32x16_f16(Ah0, bl0, acc[0][0], 0, 0, 0);
            acc[0][0] = __builtin_amdgcn_mfma_f32_32x32x16_f16(Ah0, bh0, acc[0][0], 0, 0, 0);
            acc[0][1] = __builtin_amdgcn_mfma_f32_32x32x16_f16(Al0, bh1, acc[0][1], 0, 0, 0);
            acc[0][1] = __builtin_amdgcn_mfma_f32_32x32x16_f16(Ah0, bl1, acc[0][1], 0, 0, 0);
            acc[0][1] = __builtin_amdgcn_mfma_f32_32x32x16_f16(Ah0, bh1, acc[0][1], 0, 0, 0);
            acc[1][0] = __builtin_amdgcn_mfma_f32_32x32x16_f16(Al1, bh0, acc[1][0], 0, 0, 0);
            acc[1][0] = __builtin_amdgcn_mfma_f32_32x32x16_f16(Ah1, bl0, acc[1][0], 0, 0, 0);
            acc[1][0] = __builtin_amdgcn_mfma_f32_32x32x16_f16(Ah1, bh0, acc[1][0], 0, 0, 0);
            acc[1][1] = __builtin_amdgcn_mfma_f32_32x32x16_f16(Al1, bh1, acc[1][1], 0, 0, 0);
            acc[1][1] = __builtin_amdgcn_mfma_f32_32x32x16_f16(Ah1, bl1, acc[1][1], 0, 0, 0);
            acc[1][1] = __builtin_amdgcn_mfma_f32_32x32x16_f16(Ah1, bh1, acc[1][1], 0, 0, 0);
        }
    }
    const float inv_scale = 1.f / 65536.f;
#pragma unroll
    for (int kh = 0; kh < 2; ++kh) {
#pragma unroll
        for (int ls = 0; ls < 2; ++ls) {
            int lcol = l0 + lb0 + ls * 32;
            if (lcol < L_LEN) {
#pragma unroll
                for (int rg = 0; rg < 16; ++rg) {
                    int k = kh * 32 + (rg & 3) + 8 * (rg >> 2) + 4 * kg;
                    out[((size_t)n * 64 + k) * L_LEN + lcol] =
                        acc[kh][ls][rg] * inv_scale + vbs[k];
                }
            }
        }
    }
}

extern "C" void kernel_launch(void* const* d_in, const int* in_sizes, int n_in,
                              void* d_out, int out_size, void* d_ws, size_t ws_size,
                              hipStream_t stream) {
    const float* x  = (const float*)d_in[0];
    const float* w1 = (const float*)d_in[1];
    const float* w2 = (const float*)d_in[2];
    const float* wA = (const float*)d_in[3];
    const float* bA = (const float*)d_in[4];
    float* out = (float*)d_out;
    char* ws = (char*)d_ws;
    const size_t HB = (size_t)64 * 64 * L_LEN * 4;   // 73,728,000 B
    float* h2     = (float*)(ws + HB);
    float* sq     = (float*)(ws + 2 * HB);            // 16 KB
    float* rowsum = (float*)(ws + 2 * HB + 16384);    // 16 KB
    unsigned int* w2fh = (unsigned int*)(ws + 2 * HB + 32768);   // 40 KB
    unsigned int* w2fl = (unsigned int*)(ws + 2 * HB + 32768 + 40960); // 40 KB
    // overlays in the first HB region:
    float* Rp    = (float*)ws;                        // 62,914,560 B
    float* Rsum  = (float*)(ws + 62914560);           //  5,242,880 B
    float* coefb = (float*)(ws + 68157440);           //    131,072 B
    unsigned int* Wfh = (unsigned int*)(ws + 68288512);           // 1,572,864 B
    unsigned int* Wfl = (unsigned int*)(ws + 68288512 + 1572864); // 1,572,864 B
    float* vbias = (float*)(ws + 71434240);           //     16,384 B

    prep_w2f_k<<<40, 256, 0, stream>>>(w2, w2fh, w2fl, sq, rowsum);
    conv12_k<<<64 * NTB, 256, 0, stream>>>(x, w1, w2fh, w2fl, h2, sq, rowsum);
    corr_k<<<64 * KSPL, 256, 0, stream>>>(h2, Rp);
    reduce_k<<<64 * 80, 256, 0, stream>>>(Rp, Rsum);
    mcoef_k<<<64, 256, 0, stream>>>(Rsum, h2, sq, rowsum, wA, bA, coefb);
    weff_k<<<64, 256, 0, stream>>>(coefb, wA, sq, bA, Wfh, Wfl, vbias);
    outconv_k<<<64 * NTB, 256, 0, stream>>>(h2, Wfh, Wfl, vbias, out);
}

// Round 5
// 325.186 us; speedup vs baseline: 1.8869x; 1.2056x over previous
//
#include <hip/hip_runtime.h>
#include <math.h>

#define L_LEN 4500
#define KSPL 12   // K-splits for corr_k
#define KT 128    // corr K-tile (elements)
#define TW 148    // corr LDS row stride in words
#define NTB 18    // ceil(4500/256) (outconv tiling)
#define TLC 128   // conv12 l-tile
#define NTC 36    // ceil(4500/128)
#define RS 72     // conv LDS plane row stride (f16 units); 16B-chunk stride 9 (odd) -> conflict-free b128

typedef _Float16 half8 __attribute__((ext_vector_type(8)));
typedef float f32x16 __attribute__((ext_vector_type(16)));

__device__ __forceinline__ half8 mk_half8(unsigned int w0, unsigned int w1,
                                          unsigned int w2, unsigned int w3) {
    union { unsigned int u[4]; half8 h; } t;
    t.u[0] = w0; t.u[1] = w1; t.u[2] = w2; t.u[3] = w3;
    return t.h;
}
__device__ __forceinline__ half8 u4_half8(uint4 v) {
    union { uint4 u; half8 h; } t; t.u = v; return t.h;
}

#define LOPAIR(a, b) (((a) & 0xffffu) | ((b) << 16))
#define HIPAIR(a, b) (((a) >> 16) | ((b) & 0xffff0000u))

// ------- prep: pack conv2 weights into MFMA A-fragment hi/lo u32 tables ------
// Also zero-inits rowsum (conv12 accumulates it atomically). sq is gone:
// it comes free from the autocorrelation diagonal R[a][a][d=2].
__global__ void prep_w2f_k(const float* __restrict__ w2,
                           unsigned int* __restrict__ w2fh,
                           unsigned int* __restrict__ w2fl,
                           float* __restrict__ rowsum) {
    int i = blockIdx.x * 256 + threadIdx.x;
    if (i < 4096) rowsum[i] = 0.f;
    if (i >= 10240) return;
    int w = i & 3;
    int t = i >> 2;
    int lane = t & 63; t >>= 6;
    int ks = t & 3; t >>= 2;          // t now 0..9
    int g = t % 5;
    int kh = t / 5;
    int k = kh * 32 + (lane & 31);
    int ci0 = ks * 16 + (lane >> 5) * 8 + w * 2;
    unsigned int hw = 0, lw = 0;
#pragma unroll
    for (int e = 0; e < 2; ++e) {
        float v = w2[(k * 64 + ci0 + e) * 5 + g];
        _Float16 hi = (_Float16)v;
        _Float16 lo = (_Float16)(v - (float)hi);
        unsigned short hb = __builtin_bit_cast(unsigned short, hi);
        unsigned short lb = __builtin_bit_cast(unsigned short, lo);
        hw |= ((unsigned int)hb) << (16 * e);
        lw |= ((unsigned int)lb) << (16 * e);
    }
    w2fh[i] = hw;
    w2fl[i] = lw;
}

// ---- conv12_k (MFMA): fused conv1(k=7) + conv2(k=5), f16 hi/lo 3-split ------
// v2: TL=128, waves split by kh (wid>>1) and col-half (wid&1). The ENTIRE
// per-wave W fragment set (5g x 4ks x hi/lo = 40 uint4 = 160 VGPR) is loaded
// ONCE at kernel start and held in registers -- the L2 latency is paid once,
// hidden under the h1 VALU phase, and the MFMA loop runs LDS+reg only.
// Epilogue: rowsum only (shfl reduce + 1 atomic per k).
__global__ __launch_bounds__(256, 2) void conv12_k(const float* __restrict__ x,
                                                   const float* __restrict__ w1,
                                                   const unsigned int* __restrict__ w2fh,
                                                   const unsigned int* __restrict__ w2fl,
                                                   float* __restrict__ h2,
                                                   float* __restrict__ rowsum) {
    __shared__ float xs[140];
    __shared__ __align__(16) _Float16 shh[132 * RS];
    __shared__ __align__(16) _Float16 shl[132 * RS];
    int b = blockIdx.x;
    int xcd = b & 7;
    int gi = xcd * 288 + (b >> 3);   // 2304/8 = 288 blocks per XCD, 8 n each
    int n = gi / NTC;
    int t = gi - n * NTC;
    int l0 = t * TLC;
    int lane = threadIdx.x & 63;
    int wid = threadIdx.x >> 6;
    int kh = wid >> 1;
    int colhalf = wid & 1;
    // ---- hoisted W-fragment loads (held in registers through the kernel) ----
    uint4 WHr[20], WLr[20];
    {
        const uint4* WH = (const uint4*)w2fh;
        const uint4* WL = (const uint4*)w2fl;
#pragma unroll
        for (int g = 0; g < 5; ++g)
#pragma unroll
            for (int ks = 0; ks < 4; ++ks) {
                WHr[g * 4 + ks] = WH[((kh * 5 + g) * 4 + ks) * 64 + lane];
                WLr[g * 4 + ks] = WL[((kh * 5 + g) * 4 + ks) * 64 + lane];
            }
    }
    const float* xr = x + (size_t)n * L_LEN;
    if (threadIdx.x < 138) {
        int l = l0 - 5 + threadIdx.x;
        xs[threadIdx.x] = (l >= 0 && l < L_LEN) ? xr[l] : 0.f;
    }
    __syncthreads();
    {
        int ci = lane;
        float w[7];
#pragma unroll
        for (int g = 0; g < 7; ++g) w[g] = w1[ci * 7 + g];
        for (int tt = 0; tt < 33; ++tt) {
            int r = wid * 33 + tt;            // 132 rows over 4 waves
            int l = l0 + r - 2;
            float a = 0.f;
            if (l >= 0 && l < L_LEN) {
#pragma unroll
                for (int g = 0; g < 7; ++g) a += w[g] * xs[r + g];
            }
            _Float16 hi = (_Float16)a;
            _Float16 lo = (_Float16)(a - (float)hi);
            shh[r * RS + ci] = hi;
            shl[r * RS + ci] = lo;
        }
    }
    __syncthreads();
    int col = lane & 31;
    int kg = lane >> 5;
    f32x16 acc[2];
#pragma unroll
    for (int ls = 0; ls < 2; ++ls)
#pragma unroll
        for (int i = 0; i < 16; ++i) acc[ls][i] = 0.f;
#pragma unroll
    for (int g = 0; g < 5; ++g) {
#pragma unroll
        for (int ks = 0; ks < 4; ++ks) {
            int off = ks * 16 + kg * 8;
            half8 Ah = u4_half8(WHr[g * 4 + ks]);
            half8 Al = u4_half8(WLr[g * 4 + ks]);
#pragma unroll
            for (int ls = 0; ls < 2; ++ls) {
                int rb = colhalf * 64 + ls * 32 + col + g;
                half8 bh = *(const half8*)&shh[rb * RS + off];
                half8 bl = *(const half8*)&shl[rb * RS + off];
                acc[ls] = __builtin_amdgcn_mfma_f32_32x32x16_f16(Al, bh, acc[ls], 0, 0, 0);
                acc[ls] = __builtin_amdgcn_mfma_f32_32x32x16_f16(Ah, bl, acc[ls], 0, 0, 0);
                acc[ls] = __builtin_amdgcn_mfma_f32_32x32x16_f16(Ah, bh, acc[ls], 0, 0, 0);
            }
        }
    }
#pragma unroll
    for (int ls = 0; ls < 2; ++ls) {
        int lcol = l0 + colhalf * 64 + ls * 32 + col;
        if (lcol < L_LEN) {
#pragma unroll
            for (int rg = 0; rg < 16; ++rg) {
                int k = kh * 32 + (rg & 3) + 8 * (rg >> 2) + 4 * kg;
                h2[((size_t)n * 64 + k) * L_LEN + lcol] = acc[ls][rg];
            }
        }
    }
    // ---- fused rowsum: per rg reduce this wave's 64 l-cols ----
#pragma unroll
    for (int rg = 0; rg < 16; ++rg) {
        float s1 = 0.f;
#pragma unroll
        for (int ls = 0; ls < 2; ++ls) {
            int lcol = l0 + colhalf * 64 + ls * 32 + col;
            if (lcol < L_LEN) s1 += acc[ls][rg];
        }
#pragma unroll
        for (int m = 16; m; m >>= 1) s1 += __shfl_xor(s1, m, 32);
        if (col == 0) {
            int k = kh * 32 + (rg & 3) + 8 * (rg >> 2) + 4 * kg;
            atomicAdd(&rowsum[n * 64 + k], s1);
        }
    }
}

// ---- corr_k (MFMA): R[a][b][d] = sum_l h2[a][l] * h2[b][l+d-2]  (OOB=0) -----
__global__ __launch_bounds__(256, 3) void corr_k(const float* __restrict__ h2,
                                                 float* __restrict__ Rp) {
    __shared__ __align__(16) unsigned int hl[64 * TW];   // 37,888 B
    int bid = blockIdx.x;
    int xcd = bid & 7;
    int r8 = bid >> 3;            // 0..95
    int n = xcd * 8 + (r8 & 7);   // all 12 splits of n share an XCD
    int s = r8 >> 3;              // 0..11
    const float* h2n = h2 + (size_t)n * 64 * L_LEN;

    int lane = threadIdx.x & 63;
    int wid = threadIdx.x >> 6;
    int a0 = (wid >> 1) * 32;
    int b0 = (wid & 1) * 32;
    int row31 = lane & 31;
    int g = lane >> 5;

    f32x16 acc[5];
#pragma unroll
    for (int d = 0; d < 5; ++d)
#pragma unroll
        for (int i = 0; i < 16; ++i) acc[d][i] = 0.f;

    int trow = threadIdx.x >> 2;   // staging row 0..63
    int tc4 = threadIdx.x & 3;     // staging chunk phase

    const unsigned int* arow = &hl[(a0 + row31) * TW + (g << 3)];
    const unsigned int* brow = &hl[(b0 + row31) * TW + (g << 3)];

    for (int tt = 0; tt < 3; ++tt) {
        int t = s + tt * KSPL;     // tile 0..35
        int l0 = t * KT;
        __syncthreads();           // protect previous tile's readers
        for (int i = 0; i < 9; ++i) {
            int c = tc4 + (i << 2);            // chunk 0..35
            int lbase = l0 - 8 + (c << 2);
            float v[4];
            if (lbase >= 0 && lbase + 3 < L_LEN) {
                float4 f = *(const float4*)(h2n + (size_t)trow * L_LEN + lbase);
                v[0] = f.x; v[1] = f.y; v[2] = f.z; v[3] = f.w;
            } else {
#pragma unroll
                for (int q = 0; q < 4; ++q) {
                    int l = lbase + q;
                    v[q] = (l >= 0 && l < L_LEN) ? h2n[(size_t)trow * L_LEN + l] : 0.f;
                }
            }
            unsigned int wv[4];
#pragma unroll
            for (int q = 0; q < 4; ++q) {
                float xv = v[q];
                _Float16 hi = (_Float16)xv;
                float hif = (float)hi;
                _Float16 lo = (_Float16)(xv - hif);
                unsigned short hb = __builtin_bit_cast(unsigned short, hi);
                unsigned short lb = __builtin_bit_cast(unsigned short, lo);
                wv[q] = (unsigned int)hb | ((unsigned int)lb << 16);
            }
            uint4 uu; uu.x = wv[0]; uu.y = wv[1]; uu.z = wv[2]; uu.w = wv[3];
            *(uint4*)&hl[trow * TW + (c << 2)] = uu;
        }
        __syncthreads();
#pragma unroll
        for (int ks = 0; ks < 8; ++ks) {
            const int u0 = 8 + ks * 16;
            uint4 va0 = *(const uint4*)(arow + u0);
            uint4 va1 = *(const uint4*)(arow + u0 + 4);
            uint4 vb0 = *(const uint4*)(brow + u0 - 4);
            uint4 vb1 = *(const uint4*)(brow + u0);
            uint4 vb2 = *(const uint4*)(brow + u0 + 4);
            uint4 vb3 = *(const uint4*)(brow + u0 + 8);
            unsigned int WA[8] = {va0.x, va0.y, va0.z, va0.w, va1.x, va1.y, va1.z, va1.w};
            unsigned int V[16] = {vb0.x, vb0.y, vb0.z, vb0.w, vb1.x, vb1.y, vb1.z, vb1.w,
                                  vb2.x, vb2.y, vb2.z, vb2.w, vb3.x, vb3.y, vb3.z, vb3.w};
            half8 Ahi = mk_half8(LOPAIR(WA[0], WA[1]), LOPAIR(WA[2], WA[3]),
                                 LOPAIR(WA[4], WA[5]), LOPAIR(WA[6], WA[7]));
            half8 Alo = mk_half8(HIPAIR(WA[0], WA[1]), HIPAIR(WA[2], WA[3]),
                                 HIPAIR(WA[4], WA[5]), HIPAIR(WA[6], WA[7]));
#pragma unroll
            for (int d = 0; d < 5; ++d) {
                half8 Bhi = mk_half8(LOPAIR(V[d + 2], V[d + 3]), LOPAIR(V[d + 4], V[d + 5]),
                                     LOPAIR(V[d + 6], V[d + 7]), LOPAIR(V[d + 8], V[d + 9]));
                half8 Blo = mk_half8(HIPAIR(V[d + 2], V[d + 3]), HIPAIR(V[d + 4], V[d + 5]),
                                     HIPAIR(V[d + 6], V[d + 7]), HIPAIR(V[d + 8], V[d + 9]));
                acc[d] = __builtin_amdgcn_mfma_f32_32x32x16_f16(Alo, Bhi, acc[d], 0, 0, 0);
                acc[d] = __builtin_amdgcn_mfma_f32_32x32x16_f16(Ahi, Blo, acc[d], 0, 0, 0);
                acc[d] = __builtin_amdgcn_mfma_f32_32x32x16_f16(Ahi, Bhi, acc[d], 0, 0, 0);
            }
        }
    }
    float* base = Rp + (size_t)(n * KSPL + s) * 20480;
#pragma unroll
    for (int d = 0; d < 5; ++d) {
#pragma unroll
        for (int rg = 0; rg < 16; ++rg) {
            int crow = (rg & 3) + 8 * (rg >> 2) + 4 * g;
            base[d * 4096 + (a0 + crow) * 64 + b0 + row31] = acc[d][rg];
        }
    }
}

// -- redT_k: sum the KSPL partials AND transpose [d][a][b] -> [a][b][d] -------
// Output Rsum2[n][a*320 + b*5 + d]: mjk_k's gather becomes 8 contiguous
// 160-B runs instead of 320 scattered cache lines.
__global__ __launch_bounds__(256) void redT_k(const float* __restrict__ Rp,
                                              float* __restrict__ Rsum2) {
    __shared__ float ldsA[1280];
    int n = blockIdx.x >> 4;
    int a0 = (blockIdx.x & 15) * 4;
    int tid = threadIdx.x;
    float sacc[5];
#pragma unroll
    for (int q = 0; q < 5; ++q) sacc[q] = 0.f;
    for (int s2 = 0; s2 < KSPL; ++s2) {
        const float* src = Rp + (size_t)(n * KSPL + s2) * 20480;
#pragma unroll
        for (int q = 0; q < 5; ++q) {
            int idx2 = q * 256 + tid;          // 0..1279
            int aL = idx2 / 320;
            int r = idx2 - 320 * aL;
            int d = r >> 6;
            int bb = r & 63;
            sacc[q] += src[d * 4096 + (a0 + aL) * 64 + bb];
        }
    }
#pragma unroll
    for (int q = 0; q < 5; ++q) ldsA[q * 256 + tid] = sacc[q];
    __syncthreads();
    float* dst = Rsum2 + (size_t)n * 20480 + a0 * 320;
#pragma unroll
    for (int q = 0; q < 5; ++q) {
        int oidx = q * 256 + tid;              // 0..1279 contiguous out
        int aL = oidx / 320;
        int rr = oidx - 320 * aL;
        int bb = rr / 5;
        int d = rr - 5 * bb;
        dst[oidx] = ldsA[aL * 320 + d * 64 + bb];
    }
}

// ---- mjk_k: M[n][c][ij] partial for one (i,j) pair -- grid 64n x 36(ij) -----
__global__ __launch_bounds__(256) void mjk_k(const float* __restrict__ Rsum2,
                                             const float* __restrict__ h2,
                                             const float* __restrict__ wA,
                                             float* __restrict__ Mout) {
    __shared__ float Rsub[320];
    __shared__ float wsA[1536];
    __shared__ float s0a[8], s1a[8], inva[8], s0b[8], s1b[8], invb[8];
    __shared__ float Mp[256];
    int bid = blockIdx.x;
    int n = bid / 36;
    int ij = bid - n * 36;
    int i = 0, rem = ij;
    while (rem >= 8 - i) { rem -= 8 - i; ++i; }
    int j = i + rem;
    int tid = threadIdx.x;
    size_t rbase = (size_t)n * 20480;
    // stage R sub-block: 8 rows of 40 contiguous floats
    {
        size_t base = rbase + (size_t)(8 * i) * 320 + (size_t)(8 * j) * 5;
        for (int fidx = tid; fidx < 320; fidx += 256)
            Rsub[fidx] = Rsum2[base + (fidx / 40) * 320 + (fidx % 40)];
    }
    for (int q = tid; q < 1536; q += 256) wsA[q] = wA[q];
    if (tid < 8) {
        int a = 8 * i + tid;
        s0a[tid] = h2[((size_t)n * 64 + a) * L_LEN + 0];
        s1a[tid] = h2[((size_t)n * 64 + a) * L_LEN + (L_LEN - 1)];
        inva[tid] = 1.f / (1.f + Rsum2[rbase + a * 325 + 2]);
    } else if (tid < 16) {
        int b = 8 * j + (tid - 8);
        s0b[tid - 8] = h2[((size_t)n * 64 + b) * L_LEN + 0];
        s1b[tid - 8] = h2[((size_t)n * 64 + b) * L_LEN + (L_LEN - 1)];
        invb[tid - 8] = 1.f / (1.f + Rsum2[rbase + b * 325 + 2]);
    }
    __syncthreads();
    int c = tid & 63;
    int sub = tid >> 6;
    float acc = 0.f;
#pragma unroll
    for (int pl = 0; pl < 2; ++pl) {
        int p = sub * 2 + pl;
        float ia = inva[p];
        float w0 = wsA[c * 24 + p * 3], w1 = wsA[c * 24 + p * 3 + 1],
              w2v = wsA[c * 24 + p * 3 + 2];
        float e1a = s1a[p], e0a = s0a[p];
#pragma unroll
        for (int pp = 0; pp < 8; ++pp) {
            float q0 = wsA[c * 24 + pp * 3], q1 = wsA[c * 24 + pp * 3 + 1],
                  q2 = wsA[c * 24 + pp * 3 + 2];
            const float* R5 = &Rsub[(p * 8 + pp) * 5];
            float term = (w2v * q0) * R5[0]
                       + (w1 * q0 + w2v * q1) * R5[1]
                       + (w0 * q0 + w1 * q1 + w2v * q2) * R5[2]
                       + (w0 * q1 + w1 * q2) * R5[3]
                       + (w0 * q2) * R5[4]
                       - (w0 * q0) * (e1a * s1b[pp])
                       - (w2v * q2) * (e0a * s0b[pp]);
            acc += ia * invb[pp] * term;
        }
    }
    Mp[tid] = acc;
    __syncthreads();
    if (tid < 64)
        Mout[((size_t)n * 64 + tid) * 36 + ij] =
            Mp[tid] + Mp[tid + 64] + Mp[tid + 128] + Mp[tid + 192];
}

// ---- routing_k: bias/SG terms + the per-(n,c) softmax routing tail ----------
__global__ __launch_bounds__(64) void routing_k(const float* __restrict__ Mout,
                                                const float* __restrict__ Rsum2,
                                                const float* __restrict__ h2,
                                                const float* __restrict__ rowsum,
                                                const float* __restrict__ wA,
                                                const float* __restrict__ bA,
                                                float* __restrict__ coefb) {
    __shared__ float s0s[64], s1s[64], Ts[64], invs[64];
    int n = blockIdx.x;
    int c = threadIdx.x;
    {
        int a = c;
        s0s[a] = h2[((size_t)n * 64 + a) * L_LEN + 0];
        s1s[a] = h2[((size_t)n * 64 + a) * L_LEN + (L_LEN - 1)];
        Ts[a]  = rowsum[n * 64 + a];
        invs[a] = 1.f / (1.f + Rsum2[(size_t)n * 20480 + a * 325 + 2]);
    }
    __syncthreads();
    float wreg[24];
#pragma unroll
    for (int q = 0; q < 24; ++q) wreg[q] = wA[c * 24 + q];
    float bc = bA[c];
    float SG[8];
#pragma unroll
    for (int i = 0; i < 8; ++i) {
        float s = 0.f;
#pragma unroll
        for (int p = 0; p < 8; ++p) {
            int a = 8 * i + p;
            float Ta = Ts[a];
            s += invs[a] * (wreg[p * 3 + 0] * (Ta - s1s[a]) +
                            wreg[p * 3 + 1] * Ta +
                            wreg[p * 3 + 2] * (Ta - s0s[a]));
        }
        SG[i] = s;
    }
    const float* Mrow = Mout + ((size_t)n * 64 + c) * 36;
    float M[36];
    {
        int k2 = 0;
#pragma unroll
        for (int i = 0; i < 8; ++i)
#pragma unroll
            for (int j = i; j < 8; ++j, ++k2)
                M[k2] = Mrow[k2] + bc * (SG[i] + SG[j]) + 4500.f * bc * bc;
    }
    float rs[8];
#pragma unroll
    for (int i = 0; i < 8; ++i) rs[i] = 0.f;
    {
        int idx2 = 0;
#pragma unroll
        for (int i = 0; i < 8; ++i)
#pragma unroll
            for (int j = i; j < 8; ++j, ++idx2) {
                rs[i] += M[idx2];
                if (j > i) rs[j] += M[idx2];
            }
    }
    float sumAll = 0.f;
#pragma unroll
    for (int i = 0; i < 8; ++i) sumAll += rs[i];
    float sqn1 = sumAll * (1.f / 64.f);
    float binv = 1.f / (8.f * (1.f + sqn1));
    float bv[8], mx = -1e30f;
#pragma unroll
    for (int i = 0; i < 8; ++i) { bv[i] = rs[i] * binv; mx = fmaxf(mx, bv[i]); }
    float e[8], se = 0.f;
#pragma unroll
    for (int i = 0; i < 8; ++i) { e[i] = expf(bv[i] - mx); se += e[i]; }
    float sinv = 1.f / se;
    float ci_[8];
#pragma unroll
    for (int i = 0; i < 8; ++i) ci_[i] = e[i] * sinv;
    float sqn2 = 0.f;
    {
        int idx2 = 0;
#pragma unroll
        for (int i = 0; i < 8; ++i)
#pragma unroll
            for (int j = i; j < 8; ++j, ++idx2)
                sqn2 += ((j > i) ? 2.f : 1.f) * ci_[i] * ci_[j] * M[idx2];
    }
    float scale = 1.f / (1.f + sqn2);
#pragma unroll
    for (int i = 0; i < 8; ++i) coefb[((size_t)n * 64 + c) * 8 + i] = ci_[i] * scale;
}

// -------- weff_k: emit Weff directly as MFMA A-fragment hi/lo tables ---------
__global__ __launch_bounds__(256) void weff_k(const float* __restrict__ coefb,
                                              const float* __restrict__ wA,
                                              const float* __restrict__ Rsum2,
                                              const float* __restrict__ bA,
                                              unsigned int* __restrict__ Wfh,
                                              unsigned int* __restrict__ Wfl,
                                              float* __restrict__ vbias) {
    __shared__ float invs[64];
    __shared__ float coefs[512];
    int n = blockIdx.x;
    if (threadIdx.x < 64)
        invs[threadIdx.x] =
            1.f / (1.f + Rsum2[(size_t)n * 20480 + threadIdx.x * 325 + 2]);
    for (int i = threadIdx.x; i < 512; i += 256) coefs[i] = coefb[(size_t)n * 512 + i];
    __syncthreads();
    for (int i = threadIdx.x; i < 6144; i += 256) {
        int w = i & 3;
        int t2 = i >> 2;
        int lane = t2 & 63; t2 >>= 6;
        int ks = t2 & 3; t2 >>= 2;     // t2 now 0..5
        int g = t2 % 3;
        int kh = t2 / 3;
        int k = kh * 32 + (lane & 31);
        int ci0 = ks * 16 + (lane >> 5) * 8 + w * 2;
        unsigned int hw = 0, lw = 0;
#pragma unroll
        for (int e = 0; e < 2; ++e) {
            int ci = ci0 + e;
            float v = coefs[k * 8 + (ci >> 3)] * wA[k * 24 + (ci & 7) * 3 + g] *
                      invs[ci] * 65536.f;
            _Float16 hi = (_Float16)v;
            _Float16 lo = (_Float16)(v - (float)hi);
            unsigned short hb = __builtin_bit_cast(unsigned short, hi);
            unsigned short lb = __builtin_bit_cast(unsigned short, lo);
            hw |= ((unsigned int)hb) << (16 * e);
            lw |= ((unsigned int)lb) << (16 * e);
        }
        Wfh[(size_t)n * 6144 + i] = hw;
        Wfl[(size_t)n * 6144 + i] = lw;
    }
    if (threadIdx.x < 64) {
        float s = 0.f;
#pragma unroll
        for (int i = 0; i < 8; ++i) s += coefb[((size_t)n * 64 + threadIdx.x) * 8 + i];
        vbias[n * 64 + threadIdx.x] = bA[threadIdx.x] * s;
    }
}

// ---- outconv_k (MFMA): out = Weff (64->64, k=3) * h2 + vbias ----------------
__global__ __launch_bounds__(256, 2) void outconv_k(const float* __restrict__ h2,
                                                    const unsigned int* __restrict__ Wfh,
                                                    const unsigned int* __restrict__ Wfl,
                                                    const float* __restrict__ vbias,
                                                    float* __restrict__ out) {
    __shared__ __align__(16) _Float16 shh[264 * RS];
    __shared__ __align__(16) _Float16 shl[264 * RS];
    __shared__ float vbs[64];
    int b = blockIdx.x;
    int xcd = b & 7;
    int gi = xcd * 144 + (b >> 3);
    int n = gi / NTB;
    int t = gi - n * NTB;
    int l0 = t * 256;
    const float* h2n = h2 + (size_t)n * 64 * L_LEN;
    if (threadIdx.x < 64) vbs[threadIdx.x] = vbias[n * 64 + threadIdx.x];
    {
        int trow = threadIdx.x >> 2;       // h2 row (ci) 0..63
        int tc4 = threadIdx.x & 3;         // chunk phase
        const float* hrow = h2n + (size_t)trow * L_LEN;
        int lb = l0 - 4;
        for (int i = 0; i < 17; ++i) {
            int c = tc4 + 4 * i;
            if (c >= 66) break;
            int lbase = lb + 4 * c;
            float v[4];
            if (lbase >= 0 && lbase + 3 < L_LEN) {
                float4 f = *(const float4*)(hrow + lbase);
                v[0] = f.x; v[1] = f.y; v[2] = f.z; v[3] = f.w;
            } else {
#pragma unroll
                for (int q = 0; q < 4; ++q) {
                    int l = lbase + q;
                    v[q] = (l >= 0 && l < L_LEN) ? hrow[l] : 0.f;
                }
            }
            int r = 4 * c;
#pragma unroll
            for (int q = 0; q < 4; ++q) {
                _Float16 hi = (_Float16)v[q];
                _Float16 lo = (_Float16)(v[q] - (float)hi);
                shh[(r + q) * RS + trow] = hi;
                shl[(r + q) * RS + trow] = lo;
            }
        }
    }
    __syncthreads();
    int lane = threadIdx.x & 63;
    int wid = threadIdx.x >> 6;
    int col = lane & 31;
    int kg = lane >> 5;
    int lb0 = wid * 64 + col;
    f32x16 acc[2][2];
#pragma unroll
    for (int a1 = 0; a1 < 2; ++a1)
#pragma unroll
        for (int a2 = 0; a2 < 2; ++a2)
#pragma unroll
            for (int i = 0; i < 16; ++i) acc[a1][a2][i] = 0.f;
    const uint4* WH = (const uint4*)(Wfh + (size_t)n * 6144);
    const uint4* WL = (const uint4*)(Wfl + (size_t)n * 6144);
#pragma unroll
    for (int g = 0; g < 3; ++g) {
#pragma unroll
        for (int ks = 0; ks < 4; ++ks) {
            uint4 ah0 = WH[((0 * 3 + g) * 4 + ks) * 64 + lane];
            uint4 ah1 = WH[((1 * 3 + g) * 4 + ks) * 64 + lane];
            uint4 al0 = WL[((0 * 3 + g) * 4 + ks) * 64 + lane];
            uint4 al1 = WL[((1 * 3 + g) * 4 + ks) * 64 + lane];
            int off = ks * 16 + kg * 8;
            int rb = lb0 + g + 3;
            half8 bh0 = *(const half8*)&shh[rb * RS + off];
            half8 bl0 = *(const half8*)&shl[rb * RS + off];
            half8 bh1 = *(const half8*)&shh[(rb + 32) * RS + off];
            half8 bl1 = *(const half8*)&shl[(rb + 32) * RS + off];
            half8 Ah0 = u4_half8(ah0), Al0 = u4_half8(al0);
            half8 Ah1 = u4_half8(ah1), Al1 = u4_half8(al1);
            acc[0][0] = __builtin_amdgcn_mfma_f32_32x32x16_f16(Al0, bh0, acc[0][0], 0, 0, 0);
            acc[0][0] = __builtin_amdgcn_mfma_f32_32x32x16_f16(Ah0, bl0, acc[0][0], 0, 0, 0);
            acc[0][0] = __builtin_amdgcn_mfma_f32_32x32x16_f16(Ah0, bh0, acc[0][0], 0, 0, 0);
            acc[0][1] = __builtin_amdgcn_mfma_f32_32x32x16_f16(Al0, bh1, acc[0][1], 0, 0, 0);
            acc[0][1] = __builtin_amdgcn_mfma_f32_32x32x16_f16(Ah0, bl1, acc[0][1], 0, 0, 0);
            acc[0][1] = __builtin_amdgcn_mfma_f32_32x32x16_f16(Ah0, bh1, acc[0][1], 0, 0, 0);
            acc[1][0] = __builtin_amdgcn_mfma_f32_32x32x16_f16(Al1, bh0, acc[1][0], 0, 0, 0);
            acc[1][0] = __builtin_amdgcn_mfma_f32_32x32x16_f16(Ah1, bl0, acc[1][0], 0, 0, 0);
            acc[1][0] = __builtin_amdgcn_mfma_f32_32x32x16_f16(Ah1, bh0, acc[1][0], 0, 0, 0);
            acc[1][1] = __builtin_amdgcn_mfma_f32_32x32x16_f16(Al1, bh1, acc[1][1], 0, 0, 0);
            acc[1][1] = __builtin_amdgcn_mfma_f32_32x32x16_f16(Ah1, bl1, acc[1][1], 0, 0, 0);
            acc[1][1] = __builtin_amdgcn_mfma_f32_32x32x16_f16(Ah1, bh1, acc[1][1], 0, 0, 0);
        }
    }
    const float inv_scale = 1.f / 65536.f;
#pragma unroll
    for (int kh = 0; kh < 2; ++kh) {
#pragma unroll
        for (int ls = 0; ls < 2; ++ls) {
            int lcol = l0 + lb0 + ls * 32;
            if (lcol < L_LEN) {
#pragma unroll
                for (int rg = 0; rg < 16; ++rg) {
                    int k = kh * 32 + (rg & 3) + 8 * (rg >> 2) + 4 * kg;
                    out[((size_t)n * 64 + k) * L_LEN + lcol] =
                        acc[kh][ls][rg] * inv_scale + vbs[k];
                }
            }
        }
    }
}

extern "C" void kernel_launch(void* const* d_in, const int* in_sizes, int n_in,
                              void* d_out, int out_size, void* d_ws, size_t ws_size,
                              hipStream_t stream) {
    const float* x  = (const float*)d_in[0];
    const float* w1 = (const float*)d_in[1];
    const float* w2 = (const float*)d_in[2];
    const float* wA = (const float*)d_in[3];
    const float* bA = (const float*)d_in[4];
    float* out = (float*)d_out;
    char* ws = (char*)d_ws;
    const size_t HB = (size_t)64 * 64 * L_LEN * 4;   // 73,728,000 B
    float* h2     = (float*)(ws + HB);
    float* rowsum = (float*)(ws + 2 * HB + 16384);    // 16 KB
    unsigned int* w2fh = (unsigned int*)(ws + 2 * HB + 32768);   // 40 KB
    unsigned int* w2fl = (unsigned int*)(ws + 2 * HB + 32768 + 40960); // 40 KB
    // overlays in the first HB region:
    float* Rp    = (float*)ws;                        // 62,914,560 B
    float* Rsum2 = (float*)(ws + 62914560);           //  5,242,880 B
    float* coefb = (float*)(ws + 68157440);           //    131,072 B
    unsigned int* Wfh = (unsigned int*)(ws + 68288512);           // 1,572,864 B
    unsigned int* Wfl = (unsigned int*)(ws + 68288512 + 1572864); // 1,572,864 B
    float* vbias = (float*)(ws + 71434240);           //     16,384 B
    float* Mout  = (float*)(ws + 71450624);           //    589,824 B

    prep_w2f_k<<<40, 256, 0, stream>>>(w2, w2fh, w2fl, rowsum);
    conv12_k<<<64 * NTC, 256, 0, stream>>>(x, w1, w2fh, w2fl, h2, rowsum);
    corr_k<<<64 * KSPL, 256, 0, stream>>>(h2, Rp);
    redT_k<<<64 * 16, 256, 0, stream>>>(Rp, Rsum2);
    mjk_k<<<64 * 36, 256, 0, stream>>>(Rsum2, h2, wA, Mout);
    routing_k<<<64, 64, 0, stream>>>(Mout, Rsum2, h2, rowsum, wA, bA, coefb);
    weff_k<<<64, 256, 0, stream>>>(coefb, wA, Rsum2, bA, Wfh, Wfl, vbias);
    outconv_k<<<64 * NTB, 256, 0, stream>>>(h2, Wfh, Wfl, vbias, out);
}